// Round 10
// baseline (116.687 us; speedup 1.0000x reference)
//
#include <hip/hip_runtime.h>
#include <math.h>

#define D_MODEL 512
#define NHEADS  8
#define NSEQ    2048
#define NBLK    16
#define NCHUNK  72          // sum over m of (m/2+1)
#define EPSF    1e-6f
#define WPLANE  262144      // 512*512 elements per weight plane

typedef _Float16 v8h __attribute__((ext_vector_type(8)));
typedef _Float16 v4h __attribute__((ext_vector_type(4)));
typedef float    v4f __attribute__((ext_vector_type(4)));

static __device__ __forceinline__ v4f mfma16h(v8h a, v8h b, v4f c) {
  return __builtin_amdgcn_mfma_f32_16x16x32_f16(a, b, c, 0, 0, 0);
}

// ---------------------------------------------------------------------------
// W[k][n] fp32 -> Wt[n][k] fp16 (4 matrices)
__global__ __launch_bounds__(256) void prep_w(const float* __restrict__ W0,
                                              const float* __restrict__ W1,
                                              const float* __restrict__ W2,
                                              const float* __restrict__ W3,
                                              _Float16* __restrict__ Wth) {
  __shared__ float T[64][68];
  const int z = blockIdx.z;
  const float* W = (z == 0) ? W0 : (z == 1) ? W1 : (z == 2) ? W2 : W3;
  const int kb = blockIdx.x * 64;
  const int nb = blockIdx.y * 64;
  const int tid = threadIdx.x;
#pragma unroll
  for (int l = 0; l < 4; ++l) {
    int f = tid + l * 256;           // 64 rows(k) x 16 float4(n)
    int row = f >> 4, c4 = f & 15;
    float4 v = *reinterpret_cast<const float4*>(&W[(size_t)(kb + row) * D_MODEL + nb + c4 * 4]);
    T[c4 * 4 + 0][row] = v.x; T[c4 * 4 + 1][row] = v.y;
    T[c4 * 4 + 2][row] = v.z; T[c4 * 4 + 3][row] = v.w;
  }
  __syncthreads();
  _Float16* oh = Wth + (size_t)z * WPLANE;
#pragma unroll
  for (int l = 0; l < 4; ++l) {
    int f = tid + l * 256;           // 64 rows(n) x 16 groups of 4(k)
    int n_ = f >> 4, k4 = f & 15;
    v4h h4;
    h4[0] = (_Float16)T[n_][k4 * 4 + 0];
    h4[1] = (_Float16)T[n_][k4 * 4 + 1];
    h4[2] = (_Float16)T[n_][k4 * 4 + 2];
    h4[3] = (_Float16)T[n_][k4 * 4 + 3];
    *reinterpret_cast<v4h*>(&oh[(size_t)(nb + n_) * D_MODEL + kb + k4 * 4]) = h4;
  }
}

// ---------------------------------------------------------------------------
// Q/K/V projections, 1-term fp16 MFMA. Norms from ROUNDED fp16 outputs.
__global__ __launch_bounds__(256) void qkv_gemm(
    const float* __restrict__ x, const _Float16* __restrict__ Wth,
    const float* __restrict__ bq, const float* __restrict__ bk,
    const float* __restrict__ bv,
    _Float16* __restrict__ Qp, _Float16* __restrict__ Kp,
    _Float16* __restrict__ Vp,
    float* __restrict__ Qn_, float* __restrict__ Kn_) {
  __shared__ _Float16 Ah[128][40], Bh[128][40];
  const int z = blockIdx.z;
  const _Float16* Bt = Wth + (size_t)z * WPLANE;
  const float* bias = (z == 0) ? bq : (z == 1) ? bk : bv;
  _Float16* outp = (z == 0) ? Qp : (z == 1) ? Kp : Vp;

  const int bx = blockIdx.x, by = blockIdx.y;
  const int tid = threadIdx.x;
  const int wid = tid >> 6, lane = tid & 63;
  const int wr = wid >> 1, wc = wid & 1;
  const int g = lane >> 4, lx = lane & 15;

  v4f acc[4][4];
#pragma unroll
  for (int i = 0; i < 4; ++i)
#pragma unroll
    for (int j = 0; j < 4; ++j) acc[i][j] = v4f{0.f, 0.f, 0.f, 0.f};

  for (int k0 = 0; k0 < 16; ++k0) {
    __syncthreads();
#pragma unroll
    for (int l = 0; l < 4; ++l) {
      int f = tid + l * 256;          // 128 rows x 8 float4 (32 k)
      int row = f >> 3, c4 = f & 7;
      float4 a = *reinterpret_cast<const float4*>(&x[(size_t)(by * 128 + row) * D_MODEL + k0 * 32 + c4 * 4]);
      Ah[row][c4 * 4 + 0] = (_Float16)a.x;
      Ah[row][c4 * 4 + 1] = (_Float16)a.y;
      Ah[row][c4 * 4 + 2] = (_Float16)a.z;
      Ah[row][c4 * 4 + 3] = (_Float16)a.w;
    }
#pragma unroll
    for (int l = 0; l < 2; ++l) {
      int f = tid + l * 256;          // 128 rows x 4 chunks of 8
      int row = f >> 2, c8 = f & 3;
      *reinterpret_cast<uint4*>(&Bh[row][c8 * 8]) =
          *reinterpret_cast<const uint4*>(&Bt[(size_t)(bx * 128 + row) * D_MODEL + k0 * 32 + c8 * 8]);
    }
    __syncthreads();
    v8h ah[4], bh[4];
#pragma unroll
    for (int i = 0; i < 4; ++i) {
      ah[i] = *reinterpret_cast<const v8h*>(&Ah[wr * 64 + i * 16 + lx][g * 8]);
      bh[i] = *reinterpret_cast<const v8h*>(&Bh[wc * 64 + i * 16 + lx][g * 8]);
    }
#pragma unroll
    for (int i = 0; i < 4; ++i)
#pragma unroll
      for (int j = 0; j < 4; ++j)
        acc[i][j] = mfma16h(ah[i], bh[j], acc[i][j]);
  }

  float np[4][4];
#pragma unroll
  for (int i = 0; i < 4; ++i)
#pragma unroll
    for (int r = 0; r < 4; ++r) np[i][r] = 0.f;

#pragma unroll
  for (int j = 0; j < 4; ++j) {
    const int col = bx * 128 + wc * 64 + j * 16 + lx;
    const float bj = bias[col];
#pragma unroll
    for (int i = 0; i < 4; ++i)
#pragma unroll
      for (int r = 0; r < 4; ++r) {
        const int row = by * 128 + wr * 64 + i * 16 + g * 4 + r;
        float v = acc[i][j][r] + bj;
        _Float16 hv = (_Float16)v;
        outp[(size_t)row * D_MODEL + col] = hv;
        float vr = (float)hv;                 // rounded value for the norm
        np[i][r] = fmaf(vr, vr, np[i][r]);
      }
  }
  if (z < 2) {
    float* Nout = (z == 0) ? Qn_ : Kn_;
    const int hh = bx * 2 + wc;               // head of this wave's 64 cols
#pragma unroll
    for (int i = 0; i < 4; ++i)
#pragma unroll
      for (int r = 0; r < 4; ++r) {
        float s = np[i][r];
        s += __shfl_xor(s, 1, 64);
        s += __shfl_xor(s, 2, 64);
        s += __shfl_xor(s, 4, 64);
        s += __shfl_xor(s, 8, 64);
        if (lx == 0)
          Nout[hh * NSEQ + by * 128 + wr * 64 + i * 16 + g * 4 + r] = s;
      }
  }
}

// ---------------------------------------------------------------------------
// Vp [n][512] fp16 -> Vtb [h][64][2048] (d-major per head); coalesced via LDS.
__global__ __launch_bounds__(256) void vt_prep(const ushort* __restrict__ Vb,
                                               ushort* __restrict__ Vtb) {
  __shared__ ushort T[64][72];
  const int nb = blockIdx.x * 64;
  const int h  = blockIdx.y;
  const int tid = threadIdx.x;
#pragma unroll
  for (int l = 0; l < 2; ++l) {
    int f = tid + l * 256;            // 64 rows(n) x 8 chunks of 8(d)
    int row = f >> 3, c8 = f & 7;
    uint4 w = *reinterpret_cast<const uint4*>(&Vb[(size_t)(nb + row) * D_MODEL + h * 64 + c8 * 8]);
    const ushort* p = reinterpret_cast<const ushort*>(&w);
#pragma unroll
    for (int j = 0; j < 8; ++j) T[c8 * 8 + j][row] = p[j];
  }
  __syncthreads();
#pragma unroll
  for (int l = 0; l < 2; ++l) {
    int f = tid + l * 256;            // 64 rows(d) x 8 chunks of 8(n)
    int d = f >> 3, n8 = f & 7;
    *reinterpret_cast<uint4*>(&Vtb[(size_t)(h * 64 + d) * NSEQ + nb + n8 * 8]) =
        *reinterpret_cast<const uint4*>(&T[d][n8 * 8]);
  }
}

// ---------------------------------------------------------------------------
// Attention. grid 576, h = bid&7 (head->XCD affinity). 512 thr = 8 waves,
// 3 WG/CU (LDS 53.2 KB). K,V LDS-staged with register prefetch; split Es.
// ALL global writes lane-contiguous: Opart stored PERMUTED
// (((w*4+td)*4+r)*64+lane -> 256B/instr), Npart via shuffle-gather (64B/wave).
__global__ __launch_bounds__(512, 6) void attn(
    const _Float16* __restrict__ Qp, const _Float16* __restrict__ Kp,
    const _Float16* __restrict__ Vtb, const float* __restrict__ Qn,
    const float* __restrict__ Kn, const float* __restrict__ cptr,
    float* __restrict__ Opart, float* __restrict__ Npart)
{
  __shared__ _Float16 Khs[128][68];
  __shared__ _Float16 Vs[64][140];
  __shared__ _Float16 Es[8][16][68];
  __shared__ float kns[128];

  const int bid = blockIdx.x;
  const int h    = bid & 7;
  const int pid2 = bid >> 3;          // chunk 0..71
  int m = 0, base = 0;
  while (base + (m / 2 + 1) <= pid2) { base += m / 2 + 1; ++m; }
  const int c  = pid2 - base;
  const int n0 = 2 * c;
  const int n1 = (n0 + 1 < m) ? n0 + 1 : m;

  const int tid  = threadIdx.x;
  const int w    = tid >> 6;
  const int lane = tid & 63;
  const int g = lane >> 4, lx = lane & 15;

  const float cc = fmaxf(fabsf(cptr[0]), 1e-6f);
  const float is = rsqrtf(cc);
  const bool is_one = (cc == 1.0f);
  const float two_cc = 2.f * cc;

  // staging indices
  const int krow = tid >> 3, kc8 = tid & 7;      // K: 128 rows x 8 chunks(8)
  const int vrow = tid >> 4, vc8 = tid & 15;     // V: 64 rows(d) x 16 chunks(8), 2x

  const _Float16* Kgh = Kp + h * 64;
  const _Float16* Vgh = Vtb + (size_t)(h * 64) * NSEQ;

  // ---- prologue: load n0 tiles, write LDS ----
  uint4 kpre0, kpre1, vpre0, vpre1;
  float knp = 0.f;
  {
    const _Float16* Kg = Kgh + (size_t)(n0 * 128) * D_MODEL;
    kpre0 = *reinterpret_cast<const uint4*>(&Kg[(size_t)krow * D_MODEL + kc8 * 8]);
    kpre1 = *reinterpret_cast<const uint4*>(&Kg[(size_t)(krow + 64) * D_MODEL + kc8 * 8]);
    vpre0 = *reinterpret_cast<const uint4*>(&Vgh[(size_t)vrow * NSEQ + n0 * 128 + vc8 * 8]);
    vpre1 = *reinterpret_cast<const uint4*>(&Vgh[(size_t)(vrow + 32) * NSEQ + n0 * 128 + vc8 * 8]);
    if (tid < 128) knp = Kn[h * NSEQ + n0 * 128 + tid];
  }
  *reinterpret_cast<uint4*>(&Khs[krow][kc8 * 8]) = kpre0;
  *reinterpret_cast<uint4*>(&Khs[krow + 64][kc8 * 8]) = kpre1;
  *reinterpret_cast<uint4*>(&Vs[vrow][vc8 * 8]) = vpre0;
  *reinterpret_cast<uint4*>(&Vs[vrow + 32][vc8 * 8]) = vpre1;
  if (tid < 128) kns[tid] = knp;
  __syncthreads();

  // Q fragments + norms from global
  v8h aQ[2];
  {
    const size_t qoff = (size_t)(m * 128 + 16 * w + lx) * D_MODEL + h * 64 + g * 8;
    aQ[0] = *reinterpret_cast<const v8h*>(&Qp[qoff]);
    aQ[1] = *reinterpret_cast<const v8h*>(&Qp[qoff + 32]);
  }
  float qnr[4], qar[4];
#pragma unroll
  for (int r = 0; r < 4; ++r) {
    qnr[r] = Qn[h * NSEQ + m * 128 + 16 * w + g * 4 + r];
    qar[r] = fmaf(-cc, qnr[r], 1.f);
  }

  v4f o_acc[4];
#pragma unroll
  for (int td = 0; td < 4; ++td) o_acc[td] = v4f{0.f, 0.f, 0.f, 0.f};
  float nrm[4] = {0.f, 0.f, 0.f, 0.f};

  for (int n = n0; n <= n1; ++n) {
    const bool more = (n < n1);
    if (more) {                       // issue n+1 loads; they fly over compute
      const _Float16* Kg = Kgh + (size_t)((n + 1) * 128) * D_MODEL;
      kpre0 = *reinterpret_cast<const uint4*>(&Kg[(size_t)krow * D_MODEL + kc8 * 8]);
      kpre1 = *reinterpret_cast<const uint4*>(&Kg[(size_t)(krow + 64) * D_MODEL + kc8 * 8]);
      vpre0 = *reinterpret_cast<const uint4*>(&Vgh[(size_t)vrow * NSEQ + (n + 1) * 128 + vc8 * 8]);
      vpre1 = *reinterpret_cast<const uint4*>(&Vgh[(size_t)(vrow + 32) * NSEQ + (n + 1) * 128 + vc8 * 8]);
      if (tid < 128) knp = Kn[h * NSEQ + (n + 1) * 128 + tid];
    }

    // ---- S = Q.K^T (1-term fp16) ----
    v4f acc[8];
    __builtin_amdgcn_s_setprio(1);
#pragma unroll
    for (int tn = 0; tn < 8; ++tn) {
      v8h b0 = *reinterpret_cast<const v8h*>(&Khs[tn * 16 + lx][g * 8]);
      v8h b1 = *reinterpret_cast<const v8h*>(&Khs[tn * 16 + lx][g * 8 + 32]);
      v4f a = v4f{0.f, 0.f, 0.f, 0.f};
      a = mfma16h(aQ[0], b0, a);
      a = mfma16h(aQ[1], b1, a);
      acc[tn] = a;
    }
    __builtin_amdgcn_s_setprio(0);

    // ---- u = arg + sqrt(arg^2-1), arg = 1 + t ----
    const bool diag = (n == m);
#pragma unroll
    for (int tn = 0; tn < 8; ++tn) {
      const int col = tn * 16 + lx;
      const float knc = kns[col];
      const float kac = fmaf(-cc, knc, 1.f);
#pragma unroll
      for (int r = 0; r < 4; ++r) {
        const int rowl = 16 * w + g * 4 + r;
        float dsq = fmaxf(fmaf(-2.f, acc[tn][r], qnr[r] + knc), 0.f);
        float den = fmaxf(qar[r] * kac, EPSF);
        float t = fmaxf(two_cc * dsq * __builtin_amdgcn_rcpf(den), EPSF);
        float u = 1.f + t + __builtin_amdgcn_sqrtf(t * (t + 2.f));
        if (diag && col > rowl) u = __builtin_inff();
        acc[tn][r] = u;
      }
    }

    // ---- full-row reduction (umin for c==1, smax otherwise) ----
    float mred[4];
    if (is_one) {
#pragma unroll
      for (int r = 0; r < 4; ++r) mred[r] = __builtin_inff();
#pragma unroll
      for (int tn = 0; tn < 8; ++tn)
#pragma unroll
        for (int r = 0; r < 4; ++r) mred[r] = fminf(mred[r], acc[tn][r]);
#pragma unroll
      for (int d = 1; d < 16; d <<= 1)
#pragma unroll
        for (int r = 0; r < 4; ++r) mred[r] = fminf(mred[r], __shfl_xor(mred[r], d, 64));
    } else {
#pragma unroll
      for (int r = 0; r < 4; ++r) mred[r] = -__builtin_inff();
#pragma unroll
      for (int tn = 0; tn < 8; ++tn)
#pragma unroll
        for (int r = 0; r < 4; ++r) {
          float s = -__logf(acc[tn][r]) * is;      // u=inf -> -inf
          acc[tn][r] = s;
          mred[r] = fmaxf(mred[r], s);
        }
#pragma unroll
      for (int d = 1; d < 16; d <<= 1)
#pragma unroll
        for (int r = 0; r < 4; ++r) mred[r] = fmaxf(mred[r], __shfl_xor(mred[r], d, 64));
    }

    // ---- two halves: exp -> Es(half) -> PV(half) ----
#pragma unroll
    for (int half = 0; half < 2; ++half) {
#pragma unroll
      for (int tn2 = 0; tn2 < 4; ++tn2) {
        const int tn = half * 4 + tn2;
#pragma unroll
        for (int r = 0; r < 4; ++r) {
          float e = is_one ? mred[r] * __builtin_amdgcn_rcpf(acc[tn][r])
                           : __expf(acc[tn][r] - mred[r]);
          nrm[r] += e;
          Es[w][g * 4 + r][tn2 * 16 + lx] = (_Float16)e;
        }
      }
      // Es is wave-private: drain this wave's ds_writes, no block barrier.
      asm volatile("s_waitcnt lgkmcnt(0)" ::: "memory");
      __builtin_amdgcn_sched_barrier(0);
      __builtin_amdgcn_s_setprio(1);
#pragma unroll
      for (int ks2 = 0; ks2 < 2; ++ks2) {
        const int ks = half * 2 + ks2;
        v8h ea = *reinterpret_cast<const v8h*>(&Es[w][lx][ks2 * 32 + g * 8]);
#pragma unroll
        for (int td = 0; td < 4; ++td) {
          v8h vb = *reinterpret_cast<const v8h*>(&Vs[td * 16 + lx][ks * 32 + g * 8]);
          o_acc[td] = mfma16h(ea, vb, o_acc[td]);
        }
      }
      __builtin_amdgcn_s_setprio(0);
    }

    if (more) {                       // swap in the prefetched tiles
      __syncthreads();                // everyone done reading Khs/Vs/kns
      *reinterpret_cast<uint4*>(&Khs[krow][kc8 * 8]) = kpre0;
      *reinterpret_cast<uint4*>(&Khs[krow + 64][kc8 * 8]) = kpre1;
      *reinterpret_cast<uint4*>(&Vs[vrow][vc8 * 8]) = vpre0;
      *reinterpret_cast<uint4*>(&Vs[vrow + 32][vc8 * 8]) = vpre1;
      if (tid < 128) kns[tid] = knp;
      __syncthreads();
    }
  }

  // ---- norm reduce across lx ----
#pragma unroll
  for (int d = 1; d < 16; d <<= 1)
#pragma unroll
    for (int r = 0; r < 4; ++r) nrm[r] += __shfl_xor(nrm[r], d, 64);

  // ---- PERMUTED Opart store: 256B contiguous per instruction ----
  float* Op = Opart + ((size_t)h * NCHUNK + pid2) * 8192;
#pragma unroll
  for (int td = 0; td < 4; ++td)
#pragma unroll
    for (int r = 0; r < 4; ++r)
      Op[(size_t)(((w * 4 + td) * 4) + r) * 64 + lane] = o_acc[td][r];

  // ---- Npart shuffle-gather: lane j<16 gets row 16w+j -> one 64B store ----
  {
    const int sel = lane & 3;
    float tmp = (sel == 0) ? nrm[0] : (sel == 1) ? nrm[1] : (sel == 2) ? nrm[2] : nrm[3];
    const int src = ((lane >> 2) & 3) * 16 + (lane & 3);
    float nval = __shfl(tmp, src, 64);
    if (lane < 16)
      Npart[((size_t)h * NCHUNK + pid2) * 128 + 16 * w + lane] = nval;
  }
}

// ---------------------------------------------------------------------------
// Sum PERMUTED fp32 partials over chunks, un-permute via LDS, normalize
// -> Of (fp16). grid (64, 8): 32 rows per WG.
__global__ __launch_bounds__(256) void reduce_o(const float* __restrict__ Opart,
                                                const float* __restrict__ Npart,
                                                _Float16* __restrict__ Of) {
  const int mq = blockIdx.x;
  const int mm = mq >> 2;
  const int rq = (mq & 3) * 32;
  const int h  = blockIdx.y;
  const int tid = threadIdx.x;
  int base = 0;
  for (int k = 0; k < mm; ++k) base += k / 2 + 1;
  const int nch = mm / 2 + 1;

  __shared__ float T[32][68];
  __shared__ float innorm[32];
  if (tid < 32) {
    float s = 0.f;
    for (int cI = 0; cI < nch; ++cI)
      s += Npart[((size_t)h * NCHUNK + base + cI) * 128 + rq + tid];
    innorm[tid] = 1.f / fmaxf(s, EPSF);
  }
  const int wbase = rq >> 4;
#pragma unroll
  for (int l = 0; l < 8; ++l) {
    int idx = tid + l * 256;          // 0..2047
    int lane = idx & 63;
    int sub  = idx >> 6;              // (wloc*4+td)*4 + r
    int r = sub & 3, td = (sub >> 2) & 3, wloc = sub >> 4;
    int w = wbase + wloc;
    const size_t off = (size_t)((w * 4 + td) * 4 + r) * 64 + lane;
    float s = 0.f;
    for (int cI = 0; cI < nch; ++cI)
      s += Opart[((size_t)h * NCHUNK + base + cI) * 8192 + off];
    int row = 16 * wloc + 4 * (lane >> 4) + r;   // local row in [0,32)
    int col = td * 16 + (lane & 15);
    T[row][col] = s;
  }
  __syncthreads();
#pragma unroll
  for (int l = 0; l < 2; ++l) {
    int f = tid + l * 256;            // 0..511 : 32 rows x 16 v4h
    int row = f >> 4, c4 = f & 15;
    float inv = innorm[row];
    v4h o4;
    o4[0] = (_Float16)(T[row][c4 * 4 + 0] * inv);
    o4[1] = (_Float16)(T[row][c4 * 4 + 1] * inv);
    o4[2] = (_Float16)(T[row][c4 * 4 + 2] * inv);
    o4[3] = (_Float16)(T[row][c4 * 4 + 3] * inv);
    *reinterpret_cast<v4h*>(
        &Of[(size_t)(mm * 128 + rq + row) * D_MODEL + h * 64 + c4 * 4]) = o4;
  }
}

// ---------------------------------------------------------------------------
// out = Of @ Wo + bo, 1-term fp16. 64x64 tiles, grid (8,32) = 256 WGs.
__global__ __launch_bounds__(256) void o_gemm(const _Float16* __restrict__ Of,
                                              const _Float16* __restrict__ Wth,
                                              const float* __restrict__ bo,
                                              float* __restrict__ out) {
  __shared__ _Float16 As[64][40], Bs[64][40];
  const _Float16* Bt = Wth + (size_t)3 * WPLANE;
  const int bx = blockIdx.x, by = blockIdx.y;
  const int tid = threadIdx.x;
  const int wid = tid >> 6, lane = tid & 63;
  const int wr = wid >> 1, wc = wid & 1;
  const int g = lane >> 4, lx = lane & 15;

  v4f acc[2][2];
#pragma unroll
  for (int i = 0; i < 2; ++i)
#pragma unroll
    for (int j = 0; j < 2; ++j) acc[i][j] = v4f{0.f, 0.f, 0.f, 0.f};

  const int srow = tid >> 2, sc8 = tid & 3;   // 64 rows x 4 chunks(8)
  for (int k0 = 0; k0 < 16; ++k0) {
    __syncthreads();
    *reinterpret_cast<uint4*>(&As[srow][sc8 * 8]) =
        *reinterpret_cast<const uint4*>(&Of[(size_t)(by * 64 + srow) * D_MODEL + k0 * 32 + sc8 * 8]);
    *reinterpret_cast<uint4*>(&Bs[srow][sc8 * 8]) =
        *reinterpret_cast<const uint4*>(&Bt[(size_t)(bx * 64 + srow) * D_MODEL + k0 * 32 + sc8 * 8]);
    __syncthreads();
    v8h ah[2], bh[2];
#pragma unroll
    for (int i = 0; i < 2; ++i) {
      ah[i] = *reinterpret_cast<const v8h*>(&As[wr * 32 + i * 16 + lx][g * 8]);
      bh[i] = *reinterpret_cast<const v8h*>(&Bs[wc * 32 + i * 16 + lx][g * 8]);
    }
#pragma unroll
    for (int i = 0; i < 2; ++i)
#pragma unroll
      for (int j = 0; j < 2; ++j)
        acc[i][j] = mfma16h(ah[i], bh[j], acc[i][j]);
  }
#pragma unroll
  for (int j = 0; j < 2; ++j) {
    const int col = bx * 64 + wc * 32 + j * 16 + lx;
    const float bj = bo[col];
#pragma unroll
    for (int i = 0; i < 2; ++i)
#pragma unroll
      for (int r = 0; r < 4; ++r) {
        const int row = by * 64 + wr * 32 + i * 16 + g * 4 + r;
        out[(size_t)row * D_MODEL + col] = acc[i][j][r] + bj;
      }
  }
}

// ---------------------------------------------------------------------------
extern "C" void kernel_launch(void* const* d_in, const int* in_sizes, int n_in,
                              void* d_out, int out_size, void* d_ws, size_t ws_size,
                              hipStream_t stream) {
  (void)in_sizes; (void)n_in; (void)out_size; (void)ws_size;
  const float* x  = (const float*)d_in[0];
  const float* cfg= (const float*)d_in[1];
  const float* Wq = (const float*)d_in[2];
  const float* bq = (const float*)d_in[3];
  const float* Wk = (const float*)d_in[4];
  const float* bk = (const float*)d_in[5];
  const float* Wv = (const float*)d_in[6];
  const float* bv = (const float*)d_in[7];
  const float* Wo = (const float*)d_in[8];
  const float* bo = (const float*)d_in[9];
  float* out = (float*)d_out;

  char* p = (char*)d_ws;
  const size_t PL = (size_t)NSEQ * D_MODEL * sizeof(_Float16);   // 2 MiB
  _Float16* Wth = (_Float16*)p;        p += 4 * (size_t)WPLANE * sizeof(_Float16);
  _Float16* Qp  = (_Float16*)p;        p += PL;
  _Float16* Kp  = (_Float16*)p;        p += PL;
  _Float16* Vp  = (_Float16*)p;        p += PL;
  _Float16* Vtb = (_Float16*)p;        p += PL;
  _Float16* Of  = (_Float16*)p;        p += PL;
  float*  Qn  = (float*)p;             p += (size_t)NHEADS * NSEQ * sizeof(float);
  float*  Kn  = (float*)p;             p += (size_t)NHEADS * NSEQ * sizeof(float);
  float*  Opart = (float*)p;           p += (size_t)NHEADS * NCHUNK * 8192 * sizeof(float);
  float*  Npart = (float*)p;

  prep_w<<<dim3(8, 8, 4), 256, 0, stream>>>(Wq, Wk, Wv, Wo, Wth);
  qkv_gemm<<<dim3(4, 16, 3), 256, 0, stream>>>(x, Wth, bq, bk, bv,
                                               Qp, Kp, Vp, Qn, Kn);
  vt_prep<<<dim3(32, 8), 256, 0, stream>>>((const ushort*)Vp, (ushort*)Vtb);
  attn<<<dim3(NCHUNK * NHEADS), 512, 0, stream>>>(Qp, Kp, Vtb, Qn, Kn, cfg,
                                                  Opart, Npart);
  reduce_o<<<dim3(64, NHEADS), 256, 0, stream>>>(Opart, Npart, Of);
  o_gemm<<<dim3(8, 32), 256, 0, stream>>>(Of, Wth, bo, out);
}

// Round 11
// 88.960 us; speedup vs baseline: 1.3117x; 1.3117x over previous
//
#include <hip/hip_runtime.h>
#include <math.h>

#define D_MODEL 512
#define NHEADS  8
#define NSEQ    2048
#define NBLK    16
#define NCHUNK  72          // sum over m of (m/2+1)
#define EPSF    1e-6f
#define WPLANE  262144      // 512*512 elements per weight plane

typedef _Float16 v8h __attribute__((ext_vector_type(8)));
typedef _Float16 v4h __attribute__((ext_vector_type(4)));
typedef float    v4f __attribute__((ext_vector_type(4)));

static __device__ __forceinline__ v4f mfma16h(v8h a, v8h b, v4f c) {
  return __builtin_amdgcn_mfma_f32_16x16x32_f16(a, b, c, 0, 0, 0);
}

// ---------------------------------------------------------------------------
// W[k][n] fp32 -> Wt[n][k] fp16 (4 matrices)
__global__ __launch_bounds__(256) void prep_w(const float* __restrict__ W0,
                                              const float* __restrict__ W1,
                                              const float* __restrict__ W2,
                                              const float* __restrict__ W3,
                                              _Float16* __restrict__ Wth) {
  __shared__ float T[64][68];
  const int z = blockIdx.z;
  const float* W = (z == 0) ? W0 : (z == 1) ? W1 : (z == 2) ? W2 : W3;
  const int kb = blockIdx.x * 64;
  const int nb = blockIdx.y * 64;
  const int tid = threadIdx.x;
#pragma unroll
  for (int l = 0; l < 4; ++l) {
    int f = tid + l * 256;           // 64 rows(k) x 16 float4(n)
    int row = f >> 4, c4 = f & 15;
    float4 v = *reinterpret_cast<const float4*>(&W[(size_t)(kb + row) * D_MODEL + nb + c4 * 4]);
    T[c4 * 4 + 0][row] = v.x; T[c4 * 4 + 1][row] = v.y;
    T[c4 * 4 + 2][row] = v.z; T[c4 * 4 + 3][row] = v.w;
  }
  __syncthreads();
  _Float16* oh = Wth + (size_t)z * WPLANE;
#pragma unroll
  for (int l = 0; l < 4; ++l) {
    int f = tid + l * 256;           // 64 rows(n) x 16 groups of 4(k)
    int n_ = f >> 4, k4 = f & 15;
    v4h h4;
    h4[0] = (_Float16)T[n_][k4 * 4 + 0];
    h4[1] = (_Float16)T[n_][k4 * 4 + 1];
    h4[2] = (_Float16)T[n_][k4 * 4 + 2];
    h4[3] = (_Float16)T[n_][k4 * 4 + 3];
    *reinterpret_cast<v4h*>(&oh[(size_t)(nb + n_) * D_MODEL + kb + k4 * 4]) = h4;
  }
}

// ---------------------------------------------------------------------------
// Q/K/V projections, 1-term fp16 MFMA. Norms from ROUNDED fp16 outputs.
__global__ __launch_bounds__(256) void qkv_gemm(
    const float* __restrict__ x, const _Float16* __restrict__ Wth,
    const float* __restrict__ bq, const float* __restrict__ bk,
    const float* __restrict__ bv,
    _Float16* __restrict__ Qp, _Float16* __restrict__ Kp,
    _Float16* __restrict__ Vp,
    float* __restrict__ Qn_, float* __restrict__ Kn_) {
  __shared__ _Float16 Ah[128][40], Bh[128][40];
  const int z = blockIdx.z;
  const _Float16* Bt = Wth + (size_t)z * WPLANE;
  const float* bias = (z == 0) ? bq : (z == 1) ? bk : bv;
  _Float16* outp = (z == 0) ? Qp : (z == 1) ? Kp : Vp;

  const int bx = blockIdx.x, by = blockIdx.y;
  const int tid = threadIdx.x;
  const int wid = tid >> 6, lane = tid & 63;
  const int wr = wid >> 1, wc = wid & 1;
  const int g = lane >> 4, lx = lane & 15;

  v4f acc[4][4];
#pragma unroll
  for (int i = 0; i < 4; ++i)
#pragma unroll
    for (int j = 0; j < 4; ++j) acc[i][j] = v4f{0.f, 0.f, 0.f, 0.f};

  for (int k0 = 0; k0 < 16; ++k0) {
    __syncthreads();
#pragma unroll
    for (int l = 0; l < 4; ++l) {
      int f = tid + l * 256;          // 128 rows x 8 float4 (32 k)
      int row = f >> 3, c4 = f & 7;
      float4 a = *reinterpret_cast<const float4*>(&x[(size_t)(by * 128 + row) * D_MODEL + k0 * 32 + c4 * 4]);
      Ah[row][c4 * 4 + 0] = (_Float16)a.x;
      Ah[row][c4 * 4 + 1] = (_Float16)a.y;
      Ah[row][c4 * 4 + 2] = (_Float16)a.z;
      Ah[row][c4 * 4 + 3] = (_Float16)a.w;
    }
#pragma unroll
    for (int l = 0; l < 2; ++l) {
      int f = tid + l * 256;          // 128 rows x 4 chunks of 8
      int row = f >> 2, c8 = f & 3;
      *reinterpret_cast<uint4*>(&Bh[row][c8 * 8]) =
          *reinterpret_cast<const uint4*>(&Bt[(size_t)(bx * 128 + row) * D_MODEL + k0 * 32 + c8 * 8]);
    }
    __syncthreads();
    v8h ah[4], bh[4];
#pragma unroll
    for (int i = 0; i < 4; ++i) {
      ah[i] = *reinterpret_cast<const v8h*>(&Ah[wr * 64 + i * 16 + lx][g * 8]);
      bh[i] = *reinterpret_cast<const v8h*>(&Bh[wc * 64 + i * 16 + lx][g * 8]);
    }
#pragma unroll
    for (int i = 0; i < 4; ++i)
#pragma unroll
      for (int j = 0; j < 4; ++j)
        acc[i][j] = mfma16h(ah[i], bh[j], acc[i][j]);
  }

  float np[4][4];
#pragma unroll
  for (int i = 0; i < 4; ++i)
#pragma unroll
    for (int r = 0; r < 4; ++r) np[i][r] = 0.f;

#pragma unroll
  for (int j = 0; j < 4; ++j) {
    const int col = bx * 128 + wc * 64 + j * 16 + lx;
    const float bj = bias[col];
#pragma unroll
    for (int i = 0; i < 4; ++i)
#pragma unroll
      for (int r = 0; r < 4; ++r) {
        const int row = by * 128 + wr * 64 + i * 16 + g * 4 + r;
        float v = acc[i][j][r] + bj;
        _Float16 hv = (_Float16)v;
        outp[(size_t)row * D_MODEL + col] = hv;
        float vr = (float)hv;                 // rounded value for the norm
        np[i][r] = fmaf(vr, vr, np[i][r]);
      }
  }
  if (z < 2) {
    float* Nout = (z == 0) ? Qn_ : Kn_;
    const int hh = bx * 2 + wc;               // head of this wave's 64 cols
#pragma unroll
    for (int i = 0; i < 4; ++i)
#pragma unroll
      for (int r = 0; r < 4; ++r) {
        float s = np[i][r];
        s += __shfl_xor(s, 1, 64);
        s += __shfl_xor(s, 2, 64);
        s += __shfl_xor(s, 4, 64);
        s += __shfl_xor(s, 8, 64);
        if (lx == 0)
          Nout[hh * NSEQ + by * 128 + wr * 64 + i * 16 + g * 4 + r] = s;
      }
  }
}

// ---------------------------------------------------------------------------
// Vp [n][512] fp16 -> Vtb [h][64][2048] (d-major per head); coalesced via LDS.
__global__ __launch_bounds__(256) void vt_prep(const ushort* __restrict__ Vb,
                                               ushort* __restrict__ Vtb) {
  __shared__ ushort T[64][72];
  const int nb = blockIdx.x * 64;
  const int h  = blockIdx.y;
  const int tid = threadIdx.x;
#pragma unroll
  for (int l = 0; l < 2; ++l) {
    int f = tid + l * 256;            // 64 rows(n) x 8 chunks of 8(d)
    int row = f >> 3, c8 = f & 7;
    uint4 w = *reinterpret_cast<const uint4*>(&Vb[(size_t)(nb + row) * D_MODEL + h * 64 + c8 * 8]);
    const ushort* p = reinterpret_cast<const ushort*>(&w);
#pragma unroll
    for (int j = 0; j < 8; ++j) T[c8 * 8 + j][row] = p[j];
  }
  __syncthreads();
#pragma unroll
  for (int l = 0; l < 2; ++l) {
    int f = tid + l * 256;            // 64 rows(d) x 8 chunks of 8(n)
    int d = f >> 3, n8 = f & 7;
    *reinterpret_cast<uint4*>(&Vtb[(size_t)(h * 64 + d) * NSEQ + nb + n8 * 8]) =
        *reinterpret_cast<const uint4*>(&T[d][n8 * 8]);
  }
}

// ---------------------------------------------------------------------------
// Attention. grid 576, h = bid&7 (head->XCD affinity). 512 thr = 8 waves,
// 2 WG/CU (LDS 70 KB, bounds(512,4)). K,V staged in LDS at swap time with
// TRANSIENT registers (no persistent prefetch -> no spill pressure).
// Opart written fp16 in a PERMUTED layout: 128B contiguous per instruction.
__global__ __launch_bounds__(512, 4) void attn(
    const _Float16* __restrict__ Qp, const _Float16* __restrict__ Kp,
    const _Float16* __restrict__ Vtb, const float* __restrict__ Qn,
    const float* __restrict__ Kn, const float* __restrict__ cptr,
    _Float16* __restrict__ Opart, float* __restrict__ Npart)
{
  __shared__ _Float16 Khs[128][68];
  __shared__ _Float16 Vs[64][136];
  __shared__ _Float16 Es[128][136];
  __shared__ float kns[128];

  const int bid = blockIdx.x;
  const int h    = bid & 7;
  const int pid2 = bid >> 3;          // chunk 0..71
  int m = 0, base = 0;
  while (base + (m / 2 + 1) <= pid2) { base += m / 2 + 1; ++m; }
  const int c  = pid2 - base;
  const int n0 = 2 * c;
  const int n1 = (n0 + 1 < m) ? n0 + 1 : m;

  const int tid  = threadIdx.x;
  const int w    = tid >> 6;
  const int lane = tid & 63;
  const int g = lane >> 4, lx = lane & 15;

  const float cc = fmaxf(fabsf(cptr[0]), 1e-6f);
  const float is = rsqrtf(cc);
  const bool is_one = (cc == 1.0f);
  const float two_cc = 2.f * cc;

  // staging indices
  const int krow = tid >> 3, kc8 = tid & 7;      // K: 128 rows x 8 chunks(8)
  const int vrow = tid >> 4, vc8 = tid & 15;     // V: 64 rows(d) x 16 chunks(8), 2x

  const _Float16* Kgh = Kp + h * 64;
  const _Float16* Vgh = Vtb + (size_t)(h * 64) * NSEQ;

  // ---- prologue: stage n0 tiles (transient regs) ----
  {
    const _Float16* Kg = Kgh + (size_t)(n0 * 128) * D_MODEL;
    uint4 k0v = *reinterpret_cast<const uint4*>(&Kg[(size_t)krow * D_MODEL + kc8 * 8]);
    uint4 k1v = *reinterpret_cast<const uint4*>(&Kg[(size_t)(krow + 64) * D_MODEL + kc8 * 8]);
    uint4 v0v = *reinterpret_cast<const uint4*>(&Vgh[(size_t)vrow * NSEQ + n0 * 128 + vc8 * 8]);
    uint4 v1v = *reinterpret_cast<const uint4*>(&Vgh[(size_t)(vrow + 32) * NSEQ + n0 * 128 + vc8 * 8]);
    *reinterpret_cast<uint4*>(&Khs[krow][kc8 * 8]) = k0v;
    *reinterpret_cast<uint4*>(&Khs[krow + 64][kc8 * 8]) = k1v;
    *reinterpret_cast<uint4*>(&Vs[vrow][vc8 * 8]) = v0v;
    *reinterpret_cast<uint4*>(&Vs[vrow + 32][vc8 * 8]) = v1v;
    if (tid < 128) kns[tid] = Kn[h * NSEQ + n0 * 128 + tid];
  }
  __syncthreads();

  // Q fragments + norms from global
  v8h aQ[2];
  {
    const size_t qoff = (size_t)(m * 128 + 16 * w + lx) * D_MODEL + h * 64 + g * 8;
    aQ[0] = *reinterpret_cast<const v8h*>(&Qp[qoff]);
    aQ[1] = *reinterpret_cast<const v8h*>(&Qp[qoff + 32]);
  }
  float qnr[4], qar[4];
#pragma unroll
  for (int r = 0; r < 4; ++r) {
    qnr[r] = Qn[h * NSEQ + m * 128 + 16 * w + g * 4 + r];
    qar[r] = fmaf(-cc, qnr[r], 1.f);
  }

  v4f o_acc[4];
#pragma unroll
  for (int td = 0; td < 4; ++td) o_acc[td] = v4f{0.f, 0.f, 0.f, 0.f};
  float nrm[4] = {0.f, 0.f, 0.f, 0.f};

  for (int n = n0; n <= n1; ++n) {
    // ---- S = Q.K^T (1-term fp16) ----
    v4f acc[8];
#pragma unroll
    for (int tn = 0; tn < 8; ++tn) {
      v8h b0 = *reinterpret_cast<const v8h*>(&Khs[tn * 16 + lx][g * 8]);
      v8h b1 = *reinterpret_cast<const v8h*>(&Khs[tn * 16 + lx][g * 8 + 32]);
      v4f a = v4f{0.f, 0.f, 0.f, 0.f};
      a = mfma16h(aQ[0], b0, a);
      a = mfma16h(aQ[1], b1, a);
      acc[tn] = a;
    }

    // ---- u = arg + sqrt(arg^2-1), arg = 1 + t ----
    const bool diag = (n == m);
#pragma unroll
    for (int tn = 0; tn < 8; ++tn) {
      const int col = tn * 16 + lx;
      const float knc = kns[col];
      const float kac = fmaf(-cc, knc, 1.f);
#pragma unroll
      for (int r = 0; r < 4; ++r) {
        const int rowl = 16 * w + g * 4 + r;
        float dsq = fmaxf(fmaf(-2.f, acc[tn][r], qnr[r] + knc), 0.f);
        float den = fmaxf(qar[r] * kac, EPSF);
        float t = fmaxf(two_cc * dsq * __builtin_amdgcn_rcpf(den), EPSF);
        float u = 1.f + t + __builtin_amdgcn_sqrtf(t * (t + 2.f));
        if (diag && col > rowl) u = __builtin_inff();
        acc[tn][r] = u;
      }
    }

    if (is_one) {
      // e = u_min / u   (exact exp(-(acosh-acosh_min)) for c=1)
      float umin[4] = {__builtin_inff(), __builtin_inff(), __builtin_inff(), __builtin_inff()};
#pragma unroll
      for (int tn = 0; tn < 8; ++tn)
#pragma unroll
        for (int r = 0; r < 4; ++r) umin[r] = fminf(umin[r], acc[tn][r]);
#pragma unroll
      for (int d = 1; d < 16; d <<= 1)
#pragma unroll
        for (int r = 0; r < 4; ++r) umin[r] = fminf(umin[r], __shfl_xor(umin[r], d, 64));
#pragma unroll
      for (int tn = 0; tn < 8; ++tn)
#pragma unroll
        for (int r = 0; r < 4; ++r) {
          float e = umin[r] * __builtin_amdgcn_rcpf(acc[tn][r]);   // inf -> 0
          nrm[r] += e;
          Es[16 * w + g * 4 + r][tn * 16 + lx] = (_Float16)e;
        }
    } else {
      float smax[4] = {-__builtin_inff(), -__builtin_inff(), -__builtin_inff(), -__builtin_inff()};
#pragma unroll
      for (int tn = 0; tn < 8; ++tn)
#pragma unroll
        for (int r = 0; r < 4; ++r) {
          float s = -__logf(acc[tn][r]) * is;      // u=inf -> -inf
          acc[tn][r] = s;
          smax[r] = fmaxf(smax[r], s);
        }
#pragma unroll
      for (int d = 1; d < 16; d <<= 1)
#pragma unroll
        for (int r = 0; r < 4; ++r) smax[r] = fmaxf(smax[r], __shfl_xor(smax[r], d, 64));
#pragma unroll
      for (int tn = 0; tn < 8; ++tn)
#pragma unroll
        for (int r = 0; r < 4; ++r) {
          float e = __expf(acc[tn][r] - smax[r]);
          nrm[r] += e;
          Es[16 * w + g * 4 + r][tn * 16 + lx] = (_Float16)e;
        }
    }
    // Es is wave-private: drain this wave's ds_writes, no block barrier.
    asm volatile("s_waitcnt lgkmcnt(0)" ::: "memory");
    __builtin_amdgcn_sched_barrier(0);

    // ---- o += E @ V (both from LDS) ----
#pragma unroll
    for (int ks = 0; ks < 4; ++ks) {
      v8h ea = *reinterpret_cast<const v8h*>(&Es[16 * w + lx][ks * 32 + g * 8]);
#pragma unroll
      for (int td = 0; td < 4; ++td) {
        v8h vb = *reinterpret_cast<const v8h*>(&Vs[td * 16 + lx][ks * 32 + g * 8]);
        o_acc[td] = mfma16h(ea, vb, o_acc[td]);
      }
    }

    if (n < n1) {                     // stage next tile (transient regs)
      __syncthreads();                // everyone done reading Khs/Vs/kns
      const _Float16* Kg = Kgh + (size_t)((n + 1) * 128) * D_MODEL;
      uint4 k0v = *reinterpret_cast<const uint4*>(&Kg[(size_t)krow * D_MODEL + kc8 * 8]);
      uint4 k1v = *reinterpret_cast<const uint4*>(&Kg[(size_t)(krow + 64) * D_MODEL + kc8 * 8]);
      uint4 v0v = *reinterpret_cast<const uint4*>(&Vgh[(size_t)vrow * NSEQ + (n + 1) * 128 + vc8 * 8]);
      uint4 v1v = *reinterpret_cast<const uint4*>(&Vgh[(size_t)(vrow + 32) * NSEQ + (n + 1) * 128 + vc8 * 8]);
      *reinterpret_cast<uint4*>(&Khs[krow][kc8 * 8]) = k0v;
      *reinterpret_cast<uint4*>(&Khs[krow + 64][kc8 * 8]) = k1v;
      *reinterpret_cast<uint4*>(&Vs[vrow][vc8 * 8]) = v0v;
      *reinterpret_cast<uint4*>(&Vs[vrow + 32][vc8 * 8]) = v1v;
      if (tid < 128) kns[tid] = Kn[h * NSEQ + (n + 1) * 128 + tid];
      __syncthreads();
    }
  }

  // ---- norm reduce across lx ----
#pragma unroll
  for (int d = 1; d < 16; d <<= 1)
#pragma unroll
    for (int r = 0; r < 4; ++r) nrm[r] += __shfl_xor(nrm[r], d, 64);

  // ---- PERMUTED fp16 Opart store: 128B contiguous per instruction ----
  _Float16* Op = Opart + ((size_t)h * NCHUNK + pid2) * 8192;
#pragma unroll
  for (int td = 0; td < 4; ++td)
#pragma unroll
    for (int r = 0; r < 4; ++r)
      Op[(size_t)(((w * 4 + td) * 4) + r) * 64 + lane] = (_Float16)o_acc[td][r];

  // ---- Npart shuffle-gather: lane j<16 gets row 16w+j -> one 64B store ----
  {
    const int sel = lane & 3;
    float tmp = (sel == 0) ? nrm[0] : (sel == 1) ? nrm[1] : (sel == 2) ? nrm[2] : nrm[3];
    const int src = ((lane >> 2) & 3) * 16 + (lane & 3);
    float nval = __shfl(tmp, src, 64);
    if (lane < 16)
      Npart[((size_t)h * NCHUNK + pid2) * 128 + 16 * w + lane] = nval;
  }
}

// ---------------------------------------------------------------------------
// Sum PERMUTED fp16 partials over chunks, un-permute via LDS, normalize
// -> Of (fp16). grid (64, 8): 32 rows per WG.
__global__ __launch_bounds__(256) void reduce_o(const _Float16* __restrict__ Opart,
                                                const float* __restrict__ Npart,
                                                _Float16* __restrict__ Of) {
  const int mq = blockIdx.x;
  const int mm = mq >> 2;
  const int rq = (mq & 3) * 32;
  const int h  = blockIdx.y;
  const int tid = threadIdx.x;
  int base = 0;
  for (int k = 0; k < mm; ++k) base += k / 2 + 1;
  const int nch = mm / 2 + 1;

  __shared__ float T[32][68];
  __shared__ float innorm[32];
  if (tid < 32) {
    float s = 0.f;
    for (int cI = 0; cI < nch; ++cI)
      s += Npart[((size_t)h * NCHUNK + base + cI) * 128 + rq + tid];
    innorm[tid] = 1.f / fmaxf(s, EPSF);
  }
  const int wbase = rq >> 4;
#pragma unroll
  for (int l = 0; l < 8; ++l) {
    int idx = tid + l * 256;          // 0..2047
    int lane = idx & 63;
    int sub  = idx >> 6;              // (wloc*4+td)*4 + r
    int r = sub & 3, td = (sub >> 2) & 3, wloc = sub >> 4;
    int w = wbase + wloc;
    const size_t off = (size_t)((w * 4 + td) * 4 + r) * 64 + lane;
    float s = 0.f;
    for (int cI = 0; cI < nch; ++cI)
      s += (float)Opart[((size_t)h * NCHUNK + base + cI) * 8192 + off];
    int row = 16 * wloc + 4 * (lane >> 4) + r;   // local row in [0,32)
    int col = td * 16 + (lane & 15);
    T[row][col] = s;
  }
  __syncthreads();
#pragma unroll
  for (int l = 0; l < 2; ++l) {
    int f = tid + l * 256;            // 0..511 : 32 rows x 16 v4h
    int row = f >> 4, c4 = f & 15;
    float inv = innorm[row];
    v4h o4;
    o4[0] = (_Float16)(T[row][c4 * 4 + 0] * inv);
    o4[1] = (_Float16)(T[row][c4 * 4 + 1] * inv);
    o4[2] = (_Float16)(T[row][c4 * 4 + 2] * inv);
    o4[3] = (_Float16)(T[row][c4 * 4 + 3] * inv);
    *reinterpret_cast<v4h*>(
        &Of[(size_t)(mm * 128 + rq + row) * D_MODEL + h * 64 + c4 * 4]) = o4;
  }
}

// ---------------------------------------------------------------------------
// out = Of @ Wo + bo, 1-term fp16. 64x64 tiles, grid (8,32) = 256 WGs.
__global__ __launch_bounds__(256) void o_gemm(const _Float16* __restrict__ Of,
                                              const _Float16* __restrict__ Wth,
                                              const float* __restrict__ bo,
                                              float* __restrict__ out) {
  __shared__ _Float16 As[64][40], Bs[64][40];
  const _Float16* Bt = Wth + (size_t)3 * WPLANE;
  const int bx = blockIdx.x, by = blockIdx.y;
  const int tid = threadIdx.x;
  const int wid = tid >> 6, lane = tid & 63;
  const int wr = wid >> 1, wc = wid & 1;
  const int g = lane >> 4, lx = lane & 15;

  v4f acc[2][2];
#pragma unroll
  for (int i = 0; i < 2; ++i)
#pragma unroll
    for (int j = 0; j < 2; ++j) acc[i][j] = v4f{0.f, 0.f, 0.f, 0.f};

  const int srow = tid >> 2, sc8 = tid & 3;   // 64 rows x 4 chunks(8)
  for (int k0 = 0; k0 < 16; ++k0) {
    __syncthreads();
    *reinterpret_cast<uint4*>(&As[srow][sc8 * 8]) =
        *reinterpret_cast<const uint4*>(&Of[(size_t)(by * 64 + srow) * D_MODEL + k0 * 32 + sc8 * 8]);
    *reinterpret_cast<uint4*>(&Bs[srow][sc8 * 8]) =
        *reinterpret_cast<const uint4*>(&Bt[(size_t)(bx * 64 + srow) * D_MODEL + k0 * 32 + sc8 * 8]);
    __syncthreads();
    v8h ah[2], bh[2];
#pragma unroll
    for (int i = 0; i < 2; ++i) {
      ah[i] = *reinterpret_cast<const v8h*>(&As[wr * 32 + i * 16 + lx][g * 8]);
      bh[i] = *reinterpret_cast<const v8h*>(&Bs[wc * 32 + i * 16 + lx][g * 8]);
    }
#pragma unroll
    for (int i = 0; i < 2; ++i)
#pragma unroll
      for (int j = 0; j < 2; ++j)
        acc[i][j] = mfma16h(ah[i], bh[j], acc[i][j]);
  }
#pragma unroll
  for (int j = 0; j < 2; ++j) {
    const int col = bx * 64 + wc * 32 + j * 16 + lx;
    const float bj = bo[col];
#pragma unroll
    for (int i = 0; i < 2; ++i)
#pragma unroll
      for (int r = 0; r < 4; ++r) {
        const int row = by * 64 + wr * 32 + i * 16 + g * 4 + r;
        out[(size_t)row * D_MODEL + col] = acc[i][j][r] + bj;
      }
  }
}

// ---------------------------------------------------------------------------
extern "C" void kernel_launch(void* const* d_in, const int* in_sizes, int n_in,
                              void* d_out, int out_size, void* d_ws, size_t ws_size,
                              hipStream_t stream) {
  (void)in_sizes; (void)n_in; (void)out_size; (void)ws_size;
  const float* x  = (const float*)d_in[0];
  const float* cfg= (const float*)d_in[1];
  const float* Wq = (const float*)d_in[2];
  const float* bq = (const float*)d_in[3];
  const float* Wk = (const float*)d_in[4];
  const float* bk = (const float*)d_in[5];
  const float* Wv = (const float*)d_in[6];
  const float* bv = (const float*)d_in[7];
  const float* Wo = (const float*)d_in[8];
  const float* bo = (const float*)d_in[9];
  float* out = (float*)d_out;

  char* p = (char*)d_ws;
  const size_t PL = (size_t)NSEQ * D_MODEL * sizeof(_Float16);   // 2 MiB
  _Float16* Wth = (_Float16*)p;        p += 4 * (size_t)WPLANE * sizeof(_Float16);
  _Float16* Qp  = (_Float16*)p;        p += PL;
  _Float16* Kp  = (_Float16*)p;        p += PL;
  _Float16* Vp  = (_Float16*)p;        p += PL;
  _Float16* Vtb = (_Float16*)p;        p += PL;
  _Float16* Of  = (_Float16*)p;        p += PL;
  float*  Qn  = (float*)p;             p += (size_t)NHEADS * NSEQ * sizeof(float);
  float*  Kn  = (float*)p;             p += (size_t)NHEADS * NSEQ * sizeof(float);
  _Float16* Opart = (_Float16*)p;      p += (size_t)NHEADS * NCHUNK * 8192 * sizeof(_Float16);
  float*  Npart = (float*)p;

  prep_w<<<dim3(8, 8, 4), 256, 0, stream>>>(Wq, Wk, Wv, Wo, Wth);
  qkv_gemm<<<dim3(4, 16, 3), 256, 0, stream>>>(x, Wth, bq, bk, bv,
                                               Qp, Kp, Vp, Qn, Kn);
  vt_prep<<<dim3(32, 8), 256, 0, stream>>>((const ushort*)Vp, (ushort*)Vtb);
  attn<<<dim3(NCHUNK * NHEADS), 512, 0, stream>>>(Qp, Kp, Vtb, Qn, Kn, cfg,
                                                  Opart, Npart);
  reduce_o<<<dim3(64, NHEADS), 256, 0, stream>>>(Opart, Npart, Of);
  o_gemm<<<dim3(8, 32), 256, 0, stream>>>(Of, Wth, bo, out);
}

// Round 12
// 88.099 us; speedup vs baseline: 1.3245x; 1.0098x over previous
//
#include <hip/hip_runtime.h>
#include <math.h>

#define D_MODEL 512
#define NHEADS  8
#define NSEQ    2048
#define NBLK    16
#define NCHUNK  72          // sum over m of (m/2+1)
#define EPSF    1e-6f
#define WPLANE  262144      // 512*512 elements per weight plane

typedef _Float16 v8h __attribute__((ext_vector_type(8)));
typedef _Float16 v4h __attribute__((ext_vector_type(4)));
typedef float    v4f __attribute__((ext_vector_type(4)));

static __device__ __forceinline__ v4f mfma16h(v8h a, v8h b, v4f c) {
  return __builtin_amdgcn_mfma_f32_16x16x32_f16(a, b, c, 0, 0, 0);
}

// ---------------------------------------------------------------------------
// x fp32 -> fp16 plane (done once; qkv reads fp16 with no cvt VALU)
__global__ __launch_bounds__(256) void prep_x(const float* __restrict__ x,
                                              _Float16* __restrict__ xh) {
  int idx = blockIdx.x * 256 + threadIdx.x;       // float4 index (1M/4)
  float4 v = reinterpret_cast<const float4*>(x)[idx];
  v4h o;
  o[0] = (_Float16)v.x; o[1] = (_Float16)v.y;
  o[2] = (_Float16)v.z; o[3] = (_Float16)v.w;
  reinterpret_cast<v4h*>(xh)[idx] = o;
}

// ---------------------------------------------------------------------------
// W[k][n] fp32 -> Wt[n][k] fp16 (4 matrices)
__global__ __launch_bounds__(256) void prep_w(const float* __restrict__ W0,
                                              const float* __restrict__ W1,
                                              const float* __restrict__ W2,
                                              const float* __restrict__ W3,
                                              _Float16* __restrict__ Wth) {
  __shared__ float T[64][68];
  const int z = blockIdx.z;
  const float* W = (z == 0) ? W0 : (z == 1) ? W1 : (z == 2) ? W2 : W3;
  const int kb = blockIdx.x * 64;
  const int nb = blockIdx.y * 64;
  const int tid = threadIdx.x;
#pragma unroll
  for (int l = 0; l < 4; ++l) {
    int f = tid + l * 256;           // 64 rows(k) x 16 float4(n)
    int row = f >> 4, c4 = f & 15;
    float4 v = *reinterpret_cast<const float4*>(&W[(size_t)(kb + row) * D_MODEL + nb + c4 * 4]);
    T[c4 * 4 + 0][row] = v.x; T[c4 * 4 + 1][row] = v.y;
    T[c4 * 4 + 2][row] = v.z; T[c4 * 4 + 3][row] = v.w;
  }
  __syncthreads();
  _Float16* oh = Wth + (size_t)z * WPLANE;
#pragma unroll
  for (int l = 0; l < 4; ++l) {
    int f = tid + l * 256;           // 64 rows(n) x 16 groups of 4(k)
    int n_ = f >> 4, k4 = f & 15;
    v4h h4;
    h4[0] = (_Float16)T[n_][k4 * 4 + 0];
    h4[1] = (_Float16)T[n_][k4 * 4 + 1];
    h4[2] = (_Float16)T[n_][k4 * 4 + 2];
    h4[3] = (_Float16)T[n_][k4 * 4 + 3];
    *reinterpret_cast<v4h*>(&oh[(size_t)(nb + n_) * D_MODEL + kb + k4 * 4]) = h4;
  }
}

// ---------------------------------------------------------------------------
// Q/K/V projections, 1-term fp16 MFMA, K-step 64 (8 staging rounds).
// Norms from ROUNDED fp16 outputs. z==2 (V): epilogue transposes the output
// tile in LDS (reusing the staging buffer) and writes Vtb[h][d][n] directly.
__global__ __launch_bounds__(256) void qkv_gemm(
    const _Float16* __restrict__ xh, const _Float16* __restrict__ Wth,
    const float* __restrict__ bq, const float* __restrict__ bk,
    const float* __restrict__ bv,
    _Float16* __restrict__ Qp, _Float16* __restrict__ Kp,
    _Float16* __restrict__ Vtb,
    float* __restrict__ Qn_, float* __restrict__ Kn_) {
  __shared__ _Float16 SH[18432];     // 36,864 B: Ah[128][72]+Bh[128][72] | Tv[128][136]
  _Float16* Ah = SH;                 // [128][72]
  _Float16* Bh = SH + 128 * 72;      // [128][72]

  const int z = blockIdx.z;
  const _Float16* Bt = Wth + (size_t)z * WPLANE;
  const float* bias = (z == 0) ? bq : (z == 1) ? bk : bv;
  _Float16* outp = (z == 0) ? Qp : Kp;

  const int bx = blockIdx.x, by = blockIdx.y;
  const int tid = threadIdx.x;
  const int wid = tid >> 6, lane = tid & 63;
  const int wr = wid >> 1, wc = wid & 1;
  const int g = lane >> 4, lx = lane & 15;

  v4f acc[4][4];
#pragma unroll
  for (int i = 0; i < 4; ++i)
#pragma unroll
    for (int j = 0; j < 4; ++j) acc[i][j] = v4f{0.f, 0.f, 0.f, 0.f};

  const int srow = tid >> 1, sc32 = (tid & 1) * 32;
  for (int k0 = 0; k0 < 8; ++k0) {   // K = 512, step 64
    __syncthreads();
    {
      const _Float16* sa = &xh[(size_t)(by * 128 + srow) * D_MODEL + k0 * 64 + sc32];
      const _Float16* sb = &Bt[(size_t)(bx * 128 + srow) * D_MODEL + k0 * 64 + sc32];
      _Float16* da = &Ah[srow * 72 + sc32];
      _Float16* db = &Bh[srow * 72 + sc32];
#pragma unroll
      for (int q = 0; q < 4; ++q) {
        *reinterpret_cast<uint4*>(da + q * 8) = *reinterpret_cast<const uint4*>(sa + q * 8);
        *reinterpret_cast<uint4*>(db + q * 8) = *reinterpret_cast<const uint4*>(sb + q * 8);
      }
    }
    __syncthreads();
    v8h ah[4][2], bh[4][2];
#pragma unroll
    for (int i = 0; i < 4; ++i) {
#pragma unroll
      for (int ks = 0; ks < 2; ++ks) {
        ah[i][ks] = *reinterpret_cast<const v8h*>(&Ah[(wr * 64 + i * 16 + lx) * 72 + ks * 32 + g * 8]);
        bh[i][ks] = *reinterpret_cast<const v8h*>(&Bh[(wc * 64 + i * 16 + lx) * 72 + ks * 32 + g * 8]);
      }
    }
#pragma unroll
    for (int i = 0; i < 4; ++i)
#pragma unroll
      for (int j = 0; j < 4; ++j) {
        acc[i][j] = mfma16h(ah[i][0], bh[j][0], acc[i][j]);
        acc[i][j] = mfma16h(ah[i][1], bh[j][1], acc[i][j]);
      }
  }

  if (z < 2) {
    // ---- Q/K epilogue: row-major store + fused norms (from rounded vals) ----
    float np[4][4];
#pragma unroll
    for (int i = 0; i < 4; ++i)
#pragma unroll
      for (int r = 0; r < 4; ++r) np[i][r] = 0.f;
#pragma unroll
    for (int j = 0; j < 4; ++j) {
      const int col = bx * 128 + wc * 64 + j * 16 + lx;
      const float bj = bias[col];
#pragma unroll
      for (int i = 0; i < 4; ++i)
#pragma unroll
        for (int r = 0; r < 4; ++r) {
          const int row = by * 128 + wr * 64 + i * 16 + g * 4 + r;
          float v = acc[i][j][r] + bj;
          _Float16 hv = (_Float16)v;
          outp[(size_t)row * D_MODEL + col] = hv;
          float vr = (float)hv;
          np[i][r] = fmaf(vr, vr, np[i][r]);
        }
    }
    float* Nout = (z == 0) ? Qn_ : Kn_;
    const int hh = bx * 2 + wc;
#pragma unroll
    for (int i = 0; i < 4; ++i)
#pragma unroll
      for (int r = 0; r < 4; ++r) {
        float s = np[i][r];
        s += __shfl_xor(s, 1, 64);
        s += __shfl_xor(s, 2, 64);
        s += __shfl_xor(s, 4, 64);
        s += __shfl_xor(s, 8, 64);
        if (lx == 0)
          Nout[hh * NSEQ + by * 128 + wr * 64 + i * 16 + g * 4 + r] = s;
      }
  } else {
    // ---- V epilogue: LDS transpose (reuse SH) then coalesced Vtb write ----
    __syncthreads();                 // done with Ah/Bh
    _Float16* Tv = SH;               // [128][136]
#pragma unroll
    for (int j = 0; j < 4; ++j) {
      const int col = wc * 64 + j * 16 + lx;       // local col 0..127
      const float bj = bias[bx * 128 + col];
#pragma unroll
      for (int i = 0; i < 4; ++i)
#pragma unroll
        for (int r = 0; r < 4; ++r) {
          const int row = wr * 64 + i * 16 + g * 4 + r;   // local row
          Tv[row * 136 + col] = (_Float16)(acc[i][j][r] + bj);
        }
    }
    __syncthreads();
#pragma unroll
    for (int l = 0; l < 8; ++l) {
      int t = tid + l * 256;         // 0..2047: col = t>>4, 8-row chunk = t&15
      int col = t >> 4, ch = t & 15;
      ushort tmp[8];
#pragma unroll
      for (int jj = 0; jj < 8; ++jj)
        tmp[jj] = ((const ushort*)Tv)[(ch * 8 + jj) * 136 + col];
      const int hh = bx * 2 + (col >> 6), d = col & 63;
      *reinterpret_cast<uint4*>(&Vtb[(size_t)(hh * 64 + d) * NSEQ + by * 128 + ch * 8]) =
          *reinterpret_cast<const uint4*>(tmp);
    }
  }
}

// ---------------------------------------------------------------------------
// Attention. grid 576, h = bid&7 (head->XCD affinity). 512 thr = 8 waves.
// LDS 53,248 B -> 3 WG/CU with launch_bounds(512,4) (VGPR 64, NO spills).
// K,V staged in LDS with TRANSIENT registers; split Es (two exp->Es->PV
// passes after one full-row reduction); Es wave-private (lgkmcnt fence).
// Opart fp16 PERMUTED (128B contiguous per store instruction).
__global__ __launch_bounds__(512, 4) void attn(
    const _Float16* __restrict__ Qp, const _Float16* __restrict__ Kp,
    const _Float16* __restrict__ Vtb, const float* __restrict__ Qn,
    const float* __restrict__ Kn, const float* __restrict__ cptr,
    _Float16* __restrict__ Opart, float* __restrict__ Npart)
{
  __shared__ _Float16 Khs[128][68];
  __shared__ _Float16 Vs[64][140];
  __shared__ _Float16 Es[8][16][68];
  __shared__ float kns[128];

  const int bid = blockIdx.x;
  const int h    = bid & 7;
  const int pid2 = bid >> 3;          // chunk 0..71
  int m = 0, base = 0;
  while (base + (m / 2 + 1) <= pid2) { base += m / 2 + 1; ++m; }
  const int c  = pid2 - base;
  const int n0 = 2 * c;
  const int n1 = (n0 + 1 < m) ? n0 + 1 : m;

  const int tid  = threadIdx.x;
  const int w    = tid >> 6;
  const int lane = tid & 63;
  const int g = lane >> 4, lx = lane & 15;

  const float cc = fmaxf(fabsf(cptr[0]), 1e-6f);
  const float is = rsqrtf(cc);
  const bool is_one = (cc == 1.0f);
  const float two_cc = 2.f * cc;

  // staging indices
  const int krow = tid >> 3, kc8 = tid & 7;      // K: 128 rows x 8 chunks(8)
  const int vrow = tid >> 4, vc8 = tid & 15;     // V: 64 rows(d) x 16 chunks(8), 2x

  const _Float16* Kgh = Kp + h * 64;
  const _Float16* Vgh = Vtb + (size_t)(h * 64) * NSEQ;

  // ---- prologue: stage n0 tiles (transient regs) ----
  {
    const _Float16* Kg = Kgh + (size_t)(n0 * 128) * D_MODEL;
    uint4 k0v = *reinterpret_cast<const uint4*>(&Kg[(size_t)krow * D_MODEL + kc8 * 8]);
    uint4 k1v = *reinterpret_cast<const uint4*>(&Kg[(size_t)(krow + 64) * D_MODEL + kc8 * 8]);
    uint4 v0v = *reinterpret_cast<const uint4*>(&Vgh[(size_t)vrow * NSEQ + n0 * 128 + vc8 * 8]);
    uint4 v1v = *reinterpret_cast<const uint4*>(&Vgh[(size_t)(vrow + 32) * NSEQ + n0 * 128 + vc8 * 8]);
    *reinterpret_cast<uint4*>(&Khs[krow][kc8 * 8]) = k0v;
    *reinterpret_cast<uint4*>(&Khs[krow + 64][kc8 * 8]) = k1v;
    *reinterpret_cast<uint4*>(&Vs[vrow][vc8 * 8]) = v0v;
    *reinterpret_cast<uint4*>(&Vs[vrow + 32][vc8 * 8]) = v1v;
    if (tid < 128) kns[tid] = Kn[h * NSEQ + n0 * 128 + tid];
  }
  __syncthreads();

  // Q fragments + norms from global
  v8h aQ[2];
  {
    const size_t qoff = (size_t)(m * 128 + 16 * w + lx) * D_MODEL + h * 64 + g * 8;
    aQ[0] = *reinterpret_cast<const v8h*>(&Qp[qoff]);
    aQ[1] = *reinterpret_cast<const v8h*>(&Qp[qoff + 32]);
  }
  float qnr[4], qar[4];
#pragma unroll
  for (int r = 0; r < 4; ++r) {
    qnr[r] = Qn[h * NSEQ + m * 128 + 16 * w + g * 4 + r];
    qar[r] = fmaf(-cc, qnr[r], 1.f);
  }

  v4f o_acc[4];
#pragma unroll
  for (int td = 0; td < 4; ++td) o_acc[td] = v4f{0.f, 0.f, 0.f, 0.f};
  float nrm[4] = {0.f, 0.f, 0.f, 0.f};

  for (int n = n0; n <= n1; ++n) {
    // ---- S = Q.K^T (1-term fp16) ----
    v4f acc[8];
#pragma unroll
    for (int tn = 0; tn < 8; ++tn) {
      v8h b0 = *reinterpret_cast<const v8h*>(&Khs[tn * 16 + lx][g * 8]);
      v8h b1 = *reinterpret_cast<const v8h*>(&Khs[tn * 16 + lx][g * 8 + 32]);
      v4f a = v4f{0.f, 0.f, 0.f, 0.f};
      a = mfma16h(aQ[0], b0, a);
      a = mfma16h(aQ[1], b1, a);
      acc[tn] = a;
    }

    // ---- u = arg + sqrt(arg^2-1), arg = 1 + t ----
    const bool diag = (n == m);
#pragma unroll
    for (int tn = 0; tn < 8; ++tn) {
      const int col = tn * 16 + lx;
      const float knc = kns[col];
      const float kac = fmaf(-cc, knc, 1.f);
#pragma unroll
      for (int r = 0; r < 4; ++r) {
        const int rowl = 16 * w + g * 4 + r;
        float dsq = fmaxf(fmaf(-2.f, acc[tn][r], qnr[r] + knc), 0.f);
        float den = fmaxf(qar[r] * kac, EPSF);
        float t = fmaxf(two_cc * dsq * __builtin_amdgcn_rcpf(den), EPSF);
        float u = 1.f + t + __builtin_amdgcn_sqrtf(t * (t + 2.f));
        if (diag && col > rowl) u = __builtin_inff();
        acc[tn][r] = u;
      }
    }

    // ---- full-row reduction (umin for c==1, smax otherwise) ----
    float mred[4];
    if (is_one) {
#pragma unroll
      for (int r = 0; r < 4; ++r) mred[r] = __builtin_inff();
#pragma unroll
      for (int tn = 0; tn < 8; ++tn)
#pragma unroll
        for (int r = 0; r < 4; ++r) mred[r] = fminf(mred[r], acc[tn][r]);
#pragma unroll
      for (int d = 1; d < 16; d <<= 1)
#pragma unroll
        for (int r = 0; r < 4; ++r) mred[r] = fminf(mred[r], __shfl_xor(mred[r], d, 64));
    } else {
#pragma unroll
      for (int r = 0; r < 4; ++r) mred[r] = -__builtin_inff();
#pragma unroll
      for (int tn = 0; tn < 8; ++tn)
#pragma unroll
        for (int r = 0; r < 4; ++r) {
          float s = -__logf(acc[tn][r]) * is;      // u=inf -> -inf
          acc[tn][r] = s;
          mred[r] = fmaxf(mred[r], s);
        }
#pragma unroll
      for (int d = 1; d < 16; d <<= 1)
#pragma unroll
        for (int r = 0; r < 4; ++r) mred[r] = fmaxf(mred[r], __shfl_xor(mred[r], d, 64));
    }

    // ---- two halves: exp -> Es(half) -> PV(half) ----
#pragma unroll
    for (int half = 0; half < 2; ++half) {
#pragma unroll
      for (int tn2 = 0; tn2 < 4; ++tn2) {
        const int tn = half * 4 + tn2;
#pragma unroll
        for (int r = 0; r < 4; ++r) {
          float e = is_one ? mred[r] * __builtin_amdgcn_rcpf(acc[tn][r])
                           : __expf(acc[tn][r] - mred[r]);
          nrm[r] += e;
          Es[w][g * 4 + r][tn2 * 16 + lx] = (_Float16)e;
        }
      }
      // Es wave-private: drain this wave's ds_writes, no block barrier.
      asm volatile("s_waitcnt lgkmcnt(0)" ::: "memory");
      __builtin_amdgcn_sched_barrier(0);
#pragma unroll
      for (int ks2 = 0; ks2 < 2; ++ks2) {
        const int ks = half * 2 + ks2;
        v8h ea = *reinterpret_cast<const v8h*>(&Es[w][lx][ks2 * 32 + g * 8]);
#pragma unroll
        for (int td = 0; td < 4; ++td) {
          v8h vb = *reinterpret_cast<const v8h*>(&Vs[td * 16 + lx][ks * 32 + g * 8]);
          o_acc[td] = mfma16h(ea, vb, o_acc[td]);
        }
      }
    }

    if (n < n1) {                     // stage next tile (transient regs)
      __syncthreads();                // everyone done reading Khs/Vs/kns
      const _Float16* Kg = Kgh + (size_t)((n + 1) * 128) * D_MODEL;
      uint4 k0v = *reinterpret_cast<const uint4*>(&Kg[(size_t)krow * D_MODEL + kc8 * 8]);
      uint4 k1v = *reinterpret_cast<const uint4*>(&Kg[(size_t)(krow + 64) * D_MODEL + kc8 * 8]);
      uint4 v0v = *reinterpret_cast<const uint4*>(&Vgh[(size_t)vrow * NSEQ + (n + 1) * 128 + vc8 * 8]);
      uint4 v1v = *reinterpret_cast<const uint4*>(&Vgh[(size_t)(vrow + 32) * NSEQ + (n + 1) * 128 + vc8 * 8]);
      *reinterpret_cast<uint4*>(&Khs[krow][kc8 * 8]) = k0v;
      *reinterpret_cast<uint4*>(&Khs[krow + 64][kc8 * 8]) = k1v;
      *reinterpret_cast<uint4*>(&Vs[vrow][vc8 * 8]) = v0v;
      *reinterpret_cast<uint4*>(&Vs[vrow + 32][vc8 * 8]) = v1v;
      if (tid < 128) kns[tid] = Kn[h * NSEQ + (n + 1) * 128 + tid];
      __syncthreads();
    }
  }

  // ---- norm reduce across lx ----
#pragma unroll
  for (int d = 1; d < 16; d <<= 1)
#pragma unroll
    for (int r = 0; r < 4; ++r) nrm[r] += __shfl_xor(nrm[r], d, 64);

  // ---- PERMUTED fp16 Opart store: 128B contiguous per instruction ----
  _Float16* Op = Opart + ((size_t)h * NCHUNK + pid2) * 8192;
#pragma unroll
  for (int td = 0; td < 4; ++td)
#pragma unroll
    for (int r = 0; r < 4; ++r)
      Op[(size_t)(((w * 4 + td) * 4) + r) * 64 + lane] = (_Float16)o_acc[td][r];

  // ---- Npart shuffle-gather: lane j<16 gets row 16w+j -> one 64B store ----
  {
    const int sel = lane & 3;
    float tmp = (sel == 0) ? nrm[0] : (sel == 1) ? nrm[1] : (sel == 2) ? nrm[2] : nrm[3];
    const int src = ((lane >> 2) & 3) * 16 + (lane & 3);
    float nval = __shfl(tmp, src, 64);
    if (lane < 16)
      Npart[((size_t)h * NCHUNK + pid2) * 128 + 16 * w + lane] = nval;
  }
}

// ---------------------------------------------------------------------------
// Sum PERMUTED fp16 partials over chunks, un-permute via LDS, normalize
// -> Of (fp16). grid (64, 8): 32 rows per WG.
__global__ __launch_bounds__(256) void reduce_o(const _Float16* __restrict__ Opart,
                                                const float* __restrict__ Npart,
                                                _Float16* __restrict__ Of) {
  const int mq = blockIdx.x;
  const int mm = mq >> 2;
  const int rq = (mq & 3) * 32;
  const int h  = blockIdx.y;
  const int tid = threadIdx.x;
  int base = 0;
  for (int k = 0; k < mm; ++k) base += k / 2 + 1;
  const int nch = mm / 2 + 1;

  __shared__ float T[32][68];
  __shared__ float innorm[32];
  if (tid < 32) {
    float s = 0.f;
    for (int cI = 0; cI < nch; ++cI)
      s += Npart[((size_t)h * NCHUNK + base + cI) * 128 + rq + tid];
    innorm[tid] = 1.f / fmaxf(s, EPSF);
  }
  const int wbase = rq >> 4;
#pragma unroll
  for (int l = 0; l < 8; ++l) {
    int idx = tid + l * 256;          // 0..2047
    int lane = idx & 63;
    int sub  = idx >> 6;              // (wloc*4+td)*4 + r
    int r = sub & 3, td = (sub >> 2) & 3, wloc = sub >> 4;
    int w = wbase + wloc;
    const size_t off = (size_t)((w * 4 + td) * 4 + r) * 64 + lane;
    float s = 0.f;
    for (int cI = 0; cI < nch; ++cI)
      s += (float)Opart[((size_t)h * NCHUNK + base + cI) * 8192 + off];
    int row = 16 * wloc + 4 * (lane >> 4) + r;   // local row in [0,32)
    int col = td * 16 + (lane & 15);
    T[row][col] = s;
  }
  __syncthreads();
#pragma unroll
  for (int l = 0; l < 2; ++l) {
    int f = tid + l * 256;            // 0..511 : 32 rows x 16 v4h
    int row = f >> 4, c4 = f & 15;
    float inv = innorm[row];
    v4h o4;
    o4[0] = (_Float16)(T[row][c4 * 4 + 0] * inv);
    o4[1] = (_Float16)(T[row][c4 * 4 + 1] * inv);
    o4[2] = (_Float16)(T[row][c4 * 4 + 2] * inv);
    o4[3] = (_Float16)(T[row][c4 * 4 + 3] * inv);
    *reinterpret_cast<v4h*>(
        &Of[(size_t)(mm * 128 + rq + row) * D_MODEL + h * 64 + c4 * 4]) = o4;
  }
}

// ---------------------------------------------------------------------------
// out = Of @ Wo + bo, 1-term fp16. 64x64 tiles, grid (8,32) = 256 WGs.
__global__ __launch_bounds__(256) void o_gemm(const _Float16* __restrict__ Of,
                                              const _Float16* __restrict__ Wth,
                                              const float* __restrict__ bo,
                                              float* __restrict__ out) {
  __shared__ _Float16 As[64][40], Bs[64][40];
  const _Float16* Bt = Wth + (size_t)3 * WPLANE;
  const int bx = blockIdx.x, by = blockIdx.y;
  const int tid = threadIdx.x;
  const int wid = tid >> 6, lane = tid & 63;
  const int wr = wid >> 1, wc = wid & 1;
  const int g = lane >> 4, lx = lane & 15;

  v4f acc[2][2];
#pragma unroll
  for (int i = 0; i < 2; ++i)
#pragma unroll
    for (int j = 0; j < 2; ++j) acc[i][j] = v4f{0.f, 0.f, 0.f, 0.f};

  const int srow = tid >> 2, sc8 = tid & 3;   // 64 rows x 4 chunks(8)
  for (int k0 = 0; k0 < 16; ++k0) {
    __syncthreads();
    *reinterpret_cast<uint4*>(&As[srow][sc8 * 8]) =
        *reinterpret_cast<const uint4*>(&Of[(size_t)(by * 64 + srow) * D_MODEL + k0 * 32 + sc8 * 8]);
    *reinterpret_cast<uint4*>(&Bs[srow][sc8 * 8]) =
        *reinterpret_cast<const uint4*>(&Bt[(size_t)(bx * 64 + srow) * D_MODEL + k0 * 32 + sc8 * 8]);
    __syncthreads();
    v8h ah[2], bh[2];
#pragma unroll
    for (int i = 0; i < 2; ++i) {
      ah[i] = *reinterpret_cast<const v8h*>(&As[wr * 32 + i * 16 + lx][g * 8]);
      bh[i] = *reinterpret_cast<const v8h*>(&Bs[wc * 32 + i * 16 + lx][g * 8]);
    }
#pragma unroll
    for (int i = 0; i < 2; ++i)
#pragma unroll
      for (int j = 0; j < 2; ++j)
        acc[i][j] = mfma16h(ah[i], bh[j], acc[i][j]);
  }
#pragma unroll
  for (int j = 0; j < 2; ++j) {
    const int col = bx * 64 + wc * 32 + j * 16 + lx;
    const float bj = bo[col];
#pragma unroll
    for (int i = 0; i < 2; ++i)
#pragma unroll
      for (int r = 0; r < 4; ++r) {
        const int row = by * 64 + wr * 32 + i * 16 + g * 4 + r;
        out[(size_t)row * D_MODEL + col] = acc[i][j][r] + bj;
      }
  }
}

// ---------------------------------------------------------------------------
extern "C" void kernel_launch(void* const* d_in, const int* in_sizes, int n_in,
                              void* d_out, int out_size, void* d_ws, size_t ws_size,
                              hipStream_t stream) {
  (void)in_sizes; (void)n_in; (void)out_size; (void)ws_size;
  const float* x  = (const float*)d_in[0];
  const float* cfg= (const float*)d_in[1];
  const float* Wq = (const float*)d_in[2];
  const float* bq = (const float*)d_in[3];
  const float* Wk = (const float*)d_in[4];
  const float* bk = (const float*)d_in[5];
  const float* Wv = (const float*)d_in[6];
  const float* bv = (const float*)d_in[7];
  const float* Wo = (const float*)d_in[8];
  const float* bo = (const float*)d_in[9];
  float* out = (float*)d_out;

  char* p = (char*)d_ws;
  const size_t PL = (size_t)NSEQ * D_MODEL * sizeof(_Float16);   // 2 MiB
  _Float16* Wth = (_Float16*)p;        p += 4 * (size_t)WPLANE * sizeof(_Float16);
  _Float16* xhp = (_Float16*)p;        p += PL;
  _Float16* Qp  = (_Float16*)p;        p += PL;
  _Float16* Kp  = (_Float16*)p;        p += PL;
  _Float16* Vtb = (_Float16*)p;        p += PL;
  _Float16* Of  = (_Float16*)p;        p += PL;
  float*  Qn  = (float*)p;             p += (size_t)NHEADS * NSEQ * sizeof(float);
  float*  Kn  = (float*)p;             p += (size_t)NHEADS * NSEQ * sizeof(float);
  _Float16* Opart = (_Float16*)p;      p += (size_t)NHEADS * NCHUNK * 8192 * sizeof(_Float16);
  float*  Npart = (float*)p;

  prep_x<<<1024, 256, 0, stream>>>(x, xhp);
  prep_w<<<dim3(8, 8, 4), 256, 0, stream>>>(Wq, Wk, Wv, Wo, Wth);
  qkv_gemm<<<dim3(4, 16, 3), 256, 0, stream>>>(xhp, Wth, bq, bk, bv,
                                               Qp, Kp, Vtb, Qn, Kn);
  attn<<<dim3(NCHUNK * NHEADS), 512, 0, stream>>>(Qp, Kp, Vtb, Qn, Kn, cfg,
                                                  Opart, Npart);
  reduce_o<<<dim3(64, NHEADS), 256, 0, stream>>>(Opart, Npart, Of);
  o_gemm<<<dim3(8, 32), 256, 0, stream>>>(Of, Wth, bo, out);
}

// Round 13
// 79.668 us; speedup vs baseline: 1.4647x; 1.1058x over previous
//
#include <hip/hip_runtime.h>
#include <math.h>

#define D_MODEL 512
#define NHEADS  8
#define NSEQ    2048
#define NBLK    16
#define NCHUNK  72          // sum over m of (m/2+1)
#define EPSF    1e-6f
#define WPLANE  262144      // 512*512 elements per weight plane

typedef _Float16 v8h __attribute__((ext_vector_type(8)));
typedef _Float16 v4h __attribute__((ext_vector_type(4)));
typedef float    v4f __attribute__((ext_vector_type(4)));

static __device__ __forceinline__ v4f mfma16h(v8h a, v8h b, v4f c) {
  return __builtin_amdgcn_mfma_f32_16x16x32_f16(a, b, c, 0, 0, 0);
}

// ---------------------------------------------------------------------------
// z<4: W[k][n] fp32 -> Wt[n][k] fp16.  z==4: x fp32 -> fp16 plane.
__global__ __launch_bounds__(256) void prep_wx(const float* __restrict__ W0,
                                               const float* __restrict__ W1,
                                               const float* __restrict__ W2,
                                               const float* __restrict__ W3,
                                               const float* __restrict__ x,
                                               _Float16* __restrict__ Wth,
                                               _Float16* __restrict__ xh) {
  const int z = blockIdx.z;
  const int tid = threadIdx.x;
  if (z == 4) {
    const int wg = blockIdx.y * 8 + blockIdx.x;   // 0..63
    int base = wg * 4096 + tid;                   // float4 index space: 262144
#pragma unroll
    for (int l = 0; l < 16; ++l) {
      int idx = base + l * 256;
      float4 v = reinterpret_cast<const float4*>(x)[idx];
      v4h o;
      o[0] = (_Float16)v.x; o[1] = (_Float16)v.y;
      o[2] = (_Float16)v.z; o[3] = (_Float16)v.w;
      reinterpret_cast<v4h*>(xh)[idx] = o;
    }
    return;
  }
  __shared__ float T[64][68];
  const float* W = (z == 0) ? W0 : (z == 1) ? W1 : (z == 2) ? W2 : W3;
  const int kb = blockIdx.x * 64;
  const int nb = blockIdx.y * 64;
#pragma unroll
  for (int l = 0; l < 4; ++l) {
    int f = tid + l * 256;           // 64 rows(k) x 16 float4(n)
    int row = f >> 4, c4 = f & 15;
    float4 v = *reinterpret_cast<const float4*>(&W[(size_t)(kb + row) * D_MODEL + nb + c4 * 4]);
    T[c4 * 4 + 0][row] = v.x; T[c4 * 4 + 1][row] = v.y;
    T[c4 * 4 + 2][row] = v.z; T[c4 * 4 + 3][row] = v.w;
  }
  __syncthreads();
  _Float16* oh = Wth + (size_t)z * WPLANE;
#pragma unroll
  for (int l = 0; l < 4; ++l) {
    int f = tid + l * 256;           // 64 rows(n) x 16 groups of 4(k)
    int n_ = f >> 4, k4 = f & 15;
    v4h h4;
    h4[0] = (_Float16)T[n_][k4 * 4 + 0];
    h4[1] = (_Float16)T[n_][k4 * 4 + 1];
    h4[2] = (_Float16)T[n_][k4 * 4 + 2];
    h4[3] = (_Float16)T[n_][k4 * 4 + 3];
    *reinterpret_cast<v4h*>(&oh[(size_t)(nb + n_) * D_MODEL + kb + k4 * 4]) = h4;
  }
}

// ---------------------------------------------------------------------------
// Q/K/V projections, 64x64 tiles, grid (8,32,3) = 768 WGs (fills the chip).
// bx == head for this tile's 64 output cols. 1-term fp16 MFMA, K-step 64.
// z<2: row-major store + fused per-head norms (rounded vals, cross-wave
// combine in LDS). z==2: LDS-transpose epilogue writes Vtb[h][d][n].
__global__ __launch_bounds__(256) void qkv_gemm(
    const _Float16* __restrict__ xh, const _Float16* __restrict__ Wth,
    const float* __restrict__ bq, const float* __restrict__ bk,
    const float* __restrict__ bv,
    _Float16* __restrict__ Qp, _Float16* __restrict__ Kp,
    _Float16* __restrict__ Vtb,
    float* __restrict__ Qn_, float* __restrict__ Kn_) {
  __shared__ _Float16 Ah[64][72];
  __shared__ _Float16 Bh[64][72];
  __shared__ float npar[2][64];
  const int z = blockIdx.z;
  const _Float16* Bt = Wth + (size_t)z * WPLANE;
  const float* bias = (z == 0) ? bq : (z == 1) ? bk : bv;
  _Float16* outp = (z == 0) ? Qp : Kp;

  const int bx = blockIdx.x, by = blockIdx.y;
  const int tid = threadIdx.x;
  const int wid = tid >> 6, lane = tid & 63;
  const int wr = wid >> 1, wc = wid & 1;
  const int g = lane >> 4, lx = lane & 15;

  v4f acc[2][2];
#pragma unroll
  for (int i = 0; i < 2; ++i)
#pragma unroll
    for (int j = 0; j < 2; ++j) acc[i][j] = v4f{0.f, 0.f, 0.f, 0.f};

  for (int k0 = 0; k0 < 8; ++k0) {   // K = 512, step 64
    __syncthreads();
#pragma unroll
    for (int l = 0; l < 2; ++l) {
      int f = tid + l * 256;          // 64 rows x 8 chunks(8 fp16)
      int row = f >> 3, c8 = f & 7;
      *reinterpret_cast<uint4*>(&Ah[row][c8 * 8]) =
          *reinterpret_cast<const uint4*>(&xh[(size_t)(by * 64 + row) * D_MODEL + k0 * 64 + c8 * 8]);
      *reinterpret_cast<uint4*>(&Bh[row][c8 * 8]) =
          *reinterpret_cast<const uint4*>(&Bt[(size_t)(bx * 64 + row) * D_MODEL + k0 * 64 + c8 * 8]);
    }
    __syncthreads();
    v8h a[2][2], b[2][2];
#pragma unroll
    for (int i = 0; i < 2; ++i)
#pragma unroll
      for (int ks = 0; ks < 2; ++ks) {
        a[i][ks] = *reinterpret_cast<const v8h*>(&Ah[wr * 32 + i * 16 + lx][ks * 32 + g * 8]);
        b[i][ks] = *reinterpret_cast<const v8h*>(&Bh[wc * 32 + i * 16 + lx][ks * 32 + g * 8]);
      }
#pragma unroll
    for (int i = 0; i < 2; ++i)
#pragma unroll
      for (int j = 0; j < 2; ++j) {
        acc[i][j] = mfma16h(a[i][0], b[j][0], acc[i][j]);
        acc[i][j] = mfma16h(a[i][1], b[j][1], acc[i][j]);
      }
  }

  if (z < 2) {
    float np[2][4];
#pragma unroll
    for (int i = 0; i < 2; ++i)
#pragma unroll
      for (int r = 0; r < 4; ++r) np[i][r] = 0.f;
#pragma unroll
    for (int j = 0; j < 2; ++j) {
      const int col = bx * 64 + wc * 32 + j * 16 + lx;
      const float bj = bias[col];
#pragma unroll
      for (int i = 0; i < 2; ++i)
#pragma unroll
        for (int r = 0; r < 4; ++r) {
          const int row = by * 64 + wr * 32 + i * 16 + g * 4 + r;
          float v = acc[i][j][r] + bj;
          _Float16 hv = (_Float16)v;
          outp[(size_t)row * D_MODEL + col] = hv;
          float vr = (float)hv;
          np[i][r] = fmaf(vr, vr, np[i][r]);
        }
    }
    // lx-reduce then cross-wave (wc) combine via LDS
#pragma unroll
    for (int i = 0; i < 2; ++i)
#pragma unroll
      for (int r = 0; r < 4; ++r) {
        float s = np[i][r];
        s += __shfl_xor(s, 1, 64);
        s += __shfl_xor(s, 2, 64);
        s += __shfl_xor(s, 4, 64);
        s += __shfl_xor(s, 8, 64);
        if (lx == 0) npar[wc][wr * 32 + i * 16 + g * 4 + r] = s;
      }
    __syncthreads();
    if (tid < 64) {
      float s = npar[0][tid] + npar[1][tid];
      float* Nout = (z == 0) ? Qn_ : Kn_;
      Nout[bx * NSEQ + by * 64 + tid] = s;
    }
  } else {
    // V: transpose 64x64 tile in LDS (reuse Ah), write Vtb[h=bx][d][n]
    __syncthreads();
    _Float16* Tv = &Ah[0][0];        // [64][72]
#pragma unroll
    for (int j = 0; j < 2; ++j) {
      const int col = wc * 32 + j * 16 + lx;          // local d
      const float bj = bias[bx * 64 + col];
#pragma unroll
      for (int i = 0; i < 2; ++i)
#pragma unroll
        for (int r = 0; r < 4; ++r) {
          const int row = wr * 32 + i * 16 + g * 4 + r;   // local n
          Tv[row * 72 + col] = (_Float16)(acc[i][j][r] + bj);
        }
    }
    __syncthreads();
#pragma unroll
    for (int l = 0; l < 2; ++l) {
      int f = tid + l * 256;         // 0..511: d = f>>3, ch = f&7
      int d = f >> 3, ch = f & 7;
      ushort tmp[8];
#pragma unroll
      for (int jj = 0; jj < 8; ++jj)
        tmp[jj] = ((const ushort*)Tv)[(ch * 8 + jj) * 72 + d];
      *reinterpret_cast<uint4*>(&Vtb[(size_t)(bx * 64 + d) * NSEQ + by * 64 + ch * 8]) =
          *reinterpret_cast<const uint4*>(tmp);
    }
  }
}

// ---------------------------------------------------------------------------
// Attention (unchanged from R12). grid 576, h = bid&7. 512 thr = 8 waves,
// LDS 53,248 B -> 3 WG/CU with launch_bounds(512,4) (VGPR ~64, no spills).
__global__ __launch_bounds__(512, 4) void attn(
    const _Float16* __restrict__ Qp, const _Float16* __restrict__ Kp,
    const _Float16* __restrict__ Vtb, const float* __restrict__ Qn,
    const float* __restrict__ Kn, const float* __restrict__ cptr,
    _Float16* __restrict__ Opart, float* __restrict__ Npart)
{
  __shared__ _Float16 Khs[128][68];
  __shared__ _Float16 Vs[64][140];
  __shared__ _Float16 Es[8][16][68];
  __shared__ float kns[128];

  const int bid = blockIdx.x;
  const int h    = bid & 7;
  const int pid2 = bid >> 3;          // chunk 0..71
  int m = 0, base = 0;
  while (base + (m / 2 + 1) <= pid2) { base += m / 2 + 1; ++m; }
  const int c  = pid2 - base;
  const int n0 = 2 * c;
  const int n1 = (n0 + 1 < m) ? n0 + 1 : m;

  const int tid  = threadIdx.x;
  const int w    = tid >> 6;
  const int lane = tid & 63;
  const int g = lane >> 4, lx = lane & 15;

  const float cc = fmaxf(fabsf(cptr[0]), 1e-6f);
  const float is = rsqrtf(cc);
  const bool is_one = (cc == 1.0f);
  const float two_cc = 2.f * cc;

  const int krow = tid >> 3, kc8 = tid & 7;      // K: 128 rows x 8 chunks(8)
  const int vrow = tid >> 4, vc8 = tid & 15;     // V: 64 rows(d) x 16 chunks(8), 2x

  const _Float16* Kgh = Kp + h * 64;
  const _Float16* Vgh = Vtb + (size_t)(h * 64) * NSEQ;

  {
    const _Float16* Kg = Kgh + (size_t)(n0 * 128) * D_MODEL;
    uint4 k0v = *reinterpret_cast<const uint4*>(&Kg[(size_t)krow * D_MODEL + kc8 * 8]);
    uint4 k1v = *reinterpret_cast<const uint4*>(&Kg[(size_t)(krow + 64) * D_MODEL + kc8 * 8]);
    uint4 v0v = *reinterpret_cast<const uint4*>(&Vgh[(size_t)vrow * NSEQ + n0 * 128 + vc8 * 8]);
    uint4 v1v = *reinterpret_cast<const uint4*>(&Vgh[(size_t)(vrow + 32) * NSEQ + n0 * 128 + vc8 * 8]);
    *reinterpret_cast<uint4*>(&Khs[krow][kc8 * 8]) = k0v;
    *reinterpret_cast<uint4*>(&Khs[krow + 64][kc8 * 8]) = k1v;
    *reinterpret_cast<uint4*>(&Vs[vrow][vc8 * 8]) = v0v;
    *reinterpret_cast<uint4*>(&Vs[vrow + 32][vc8 * 8]) = v1v;
    if (tid < 128) kns[tid] = Kn[h * NSEQ + n0 * 128 + tid];
  }
  __syncthreads();

  v8h aQ[2];
  {
    const size_t qoff = (size_t)(m * 128 + 16 * w + lx) * D_MODEL + h * 64 + g * 8;
    aQ[0] = *reinterpret_cast<const v8h*>(&Qp[qoff]);
    aQ[1] = *reinterpret_cast<const v8h*>(&Qp[qoff + 32]);
  }
  float qnr[4], qar[4];
#pragma unroll
  for (int r = 0; r < 4; ++r) {
    qnr[r] = Qn[h * NSEQ + m * 128 + 16 * w + g * 4 + r];
    qar[r] = fmaf(-cc, qnr[r], 1.f);
  }

  v4f o_acc[4];
#pragma unroll
  for (int td = 0; td < 4; ++td) o_acc[td] = v4f{0.f, 0.f, 0.f, 0.f};
  float nrm[4] = {0.f, 0.f, 0.f, 0.f};

  for (int n = n0; n <= n1; ++n) {
    v4f acc[8];
#pragma unroll
    for (int tn = 0; tn < 8; ++tn) {
      v8h b0 = *reinterpret_cast<const v8h*>(&Khs[tn * 16 + lx][g * 8]);
      v8h b1 = *reinterpret_cast<const v8h*>(&Khs[tn * 16 + lx][g * 8 + 32]);
      v4f a = v4f{0.f, 0.f, 0.f, 0.f};
      a = mfma16h(aQ[0], b0, a);
      a = mfma16h(aQ[1], b1, a);
      acc[tn] = a;
    }

    const bool diag = (n == m);
#pragma unroll
    for (int tn = 0; tn < 8; ++tn) {
      const int col = tn * 16 + lx;
      const float knc = kns[col];
      const float kac = fmaf(-cc, knc, 1.f);
#pragma unroll
      for (int r = 0; r < 4; ++r) {
        const int rowl = 16 * w + g * 4 + r;
        float dsq = fmaxf(fmaf(-2.f, acc[tn][r], qnr[r] + knc), 0.f);
        float den = fmaxf(qar[r] * kac, EPSF);
        float t = fmaxf(two_cc * dsq * __builtin_amdgcn_rcpf(den), EPSF);
        float u = 1.f + t + __builtin_amdgcn_sqrtf(t * (t + 2.f));
        if (diag && col > rowl) u = __builtin_inff();
        acc[tn][r] = u;
      }
    }

    float mred[4];
    if (is_one) {
#pragma unroll
      for (int r = 0; r < 4; ++r) mred[r] = __builtin_inff();
#pragma unroll
      for (int tn = 0; tn < 8; ++tn)
#pragma unroll
        for (int r = 0; r < 4; ++r) mred[r] = fminf(mred[r], acc[tn][r]);
#pragma unroll
      for (int d = 1; d < 16; d <<= 1)
#pragma unroll
        for (int r = 0; r < 4; ++r) mred[r] = fminf(mred[r], __shfl_xor(mred[r], d, 64));
    } else {
#pragma unroll
      for (int r = 0; r < 4; ++r) mred[r] = -__builtin_inff();
#pragma unroll
      for (int tn = 0; tn < 8; ++tn)
#pragma unroll
        for (int r = 0; r < 4; ++r) {
          float s = -__logf(acc[tn][r]) * is;
          acc[tn][r] = s;
          mred[r] = fmaxf(mred[r], s);
        }
#pragma unroll
      for (int d = 1; d < 16; d <<= 1)
#pragma unroll
        for (int r = 0; r < 4; ++r) mred[r] = fmaxf(mred[r], __shfl_xor(mred[r], d, 64));
    }

#pragma unroll
    for (int half = 0; half < 2; ++half) {
#pragma unroll
      for (int tn2 = 0; tn2 < 4; ++tn2) {
        const int tn = half * 4 + tn2;
#pragma unroll
        for (int r = 0; r < 4; ++r) {
          float e = is_one ? mred[r] * __builtin_amdgcn_rcpf(acc[tn][r])
                           : __expf(acc[tn][r] - mred[r]);
          nrm[r] += e;
          Es[w][g * 4 + r][tn2 * 16 + lx] = (_Float16)e;
        }
      }
      asm volatile("s_waitcnt lgkmcnt(0)" ::: "memory");
      __builtin_amdgcn_sched_barrier(0);
#pragma unroll
      for (int ks2 = 0; ks2 < 2; ++ks2) {
        const int ks = half * 2 + ks2;
        v8h ea = *reinterpret_cast<const v8h*>(&Es[w][lx][ks2 * 32 + g * 8]);
#pragma unroll
        for (int td = 0; td < 4; ++td) {
          v8h vb = *reinterpret_cast<const v8h*>(&Vs[td * 16 + lx][ks * 32 + g * 8]);
          o_acc[td] = mfma16h(ea, vb, o_acc[td]);
        }
      }
    }

    if (n < n1) {
      __syncthreads();
      const _Float16* Kg = Kgh + (size_t)((n + 1) * 128) * D_MODEL;
      uint4 k0v = *reinterpret_cast<const uint4*>(&Kg[(size_t)krow * D_MODEL + kc8 * 8]);
      uint4 k1v = *reinterpret_cast<const uint4*>(&Kg[(size_t)(krow + 64) * D_MODEL + kc8 * 8]);
      uint4 v0v = *reinterpret_cast<const uint4*>(&Vgh[(size_t)vrow * NSEQ + (n + 1) * 128 + vc8 * 8]);
      uint4 v1v = *reinterpret_cast<const uint4*>(&Vgh[(size_t)(vrow + 32) * NSEQ + (n + 1) * 128 + vc8 * 8]);
      *reinterpret_cast<uint4*>(&Khs[krow][kc8 * 8]) = k0v;
      *reinterpret_cast<uint4*>(&Khs[krow + 64][kc8 * 8]) = k1v;
      *reinterpret_cast<uint4*>(&Vs[vrow][vc8 * 8]) = v0v;
      *reinterpret_cast<uint4*>(&Vs[vrow + 32][vc8 * 8]) = v1v;
      if (tid < 128) kns[tid] = Kn[h * NSEQ + (n + 1) * 128 + tid];
      __syncthreads();
    }
  }

#pragma unroll
  for (int d = 1; d < 16; d <<= 1)
#pragma unroll
    for (int r = 0; r < 4; ++r) nrm[r] += __shfl_xor(nrm[r], d, 64);

  _Float16* Op = Opart + ((size_t)h * NCHUNK + pid2) * 8192;
#pragma unroll
  for (int td = 0; td < 4; ++td)
#pragma unroll
    for (int r = 0; r < 4; ++r)
      Op[(size_t)(((w * 4 + td) * 4) + r) * 64 + lane] = (_Float16)o_acc[td][r];

  {
    const int sel = lane & 3;
    float tmp = (sel == 0) ? nrm[0] : (sel == 1) ? nrm[1] : (sel == 2) ? nrm[2] : nrm[3];
    const int src = ((lane >> 2) & 3) * 16 + (lane & 3);
    float nval = __shfl(tmp, src, 64);
    if (lane < 16)
      Npart[((size_t)h * NCHUNK + pid2) * 128 + 16 * w + lane] = nval;
  }
}

// ---------------------------------------------------------------------------
// Sum PERMUTED fp16 partials over chunks, un-permute via LDS, normalize
// -> Of (fp16). grid (64, 8): 32 rows per WG. (unchanged from R12)
__global__ __launch_bounds__(256) void reduce_o(const _Float16* __restrict__ Opart,
                                                const float* __restrict__ Npart,
                                                _Float16* __restrict__ Of) {
  const int mq = blockIdx.x;
  const int mm = mq >> 2;
  const int rq = (mq & 3) * 32;
  const int h  = blockIdx.y;
  const int tid = threadIdx.x;
  int base = 0;
  for (int k = 0; k < mm; ++k) base += k / 2 + 1;
  const int nch = mm / 2 + 1;

  __shared__ float T[32][68];
  __shared__ float innorm[32];
  if (tid < 32) {
    float s = 0.f;
    for (int cI = 0; cI < nch; ++cI)
      s += Npart[((size_t)h * NCHUNK + base + cI) * 128 + rq + tid];
    innorm[tid] = 1.f / fmaxf(s, EPSF);
  }
  const int wbase = rq >> 4;
#pragma unroll
  for (int l = 0; l < 8; ++l) {
    int idx = tid + l * 256;          // 0..2047
    int lane = idx & 63;
    int sub  = idx >> 6;              // (wloc*4+td)*4 + r
    int r = sub & 3, td = (sub >> 2) & 3, wloc = sub >> 4;
    int w = wbase + wloc;
    const size_t off = (size_t)((w * 4 + td) * 4 + r) * 64 + lane;
    float s = 0.f;
    for (int cI = 0; cI < nch; ++cI)
      s += (float)Opart[((size_t)h * NCHUNK + base + cI) * 8192 + off];
    int row = 16 * wloc + 4 * (lane >> 4) + r;   // local row in [0,32)
    int col = td * 16 + (lane & 15);
    T[row][col] = s;
  }
  __syncthreads();
#pragma unroll
  for (int l = 0; l < 2; ++l) {
    int f = tid + l * 256;            // 0..511 : 32 rows x 16 v4h
    int row = f >> 4, c4 = f & 15;
    float inv = innorm[row];
    v4h o4;
    o4[0] = (_Float16)(T[row][c4 * 4 + 0] * inv);
    o4[1] = (_Float16)(T[row][c4 * 4 + 1] * inv);
    o4[2] = (_Float16)(T[row][c4 * 4 + 2] * inv);
    o4[3] = (_Float16)(T[row][c4 * 4 + 3] * inv);
    *reinterpret_cast<v4h*>(
        &Of[(size_t)(mm * 128 + rq + row) * D_MODEL + h * 64 + c4 * 4]) = o4;
  }
}

// ---------------------------------------------------------------------------
// out = Of @ Wo + bo, 1-term fp16. 64x64 tiles, grid (8,32). (unchanged)
__global__ __launch_bounds__(256) void o_gemm(const _Float16* __restrict__ Of,
                                              const _Float16* __restrict__ Wth,
                                              const float* __restrict__ bo,
                                              float* __restrict__ out) {
  __shared__ _Float16 As[64][40], Bs[64][40];
  const _Float16* Bt = Wth + (size_t)3 * WPLANE;
  const int bx = blockIdx.x, by = blockIdx.y;
  const int tid = threadIdx.x;
  const int wid = tid >> 6, lane = tid & 63;
  const int wr = wid >> 1, wc = wid & 1;
  const int g = lane >> 4, lx = lane & 15;

  v4f acc[2][2];
#pragma unroll
  for (int i = 0; i < 2; ++i)
#pragma unroll
    for (int j = 0; j < 2; ++j) acc[i][j] = v4f{0.f, 0.f, 0.f, 0.f};

  const int srow = tid >> 2, sc8 = tid & 3;   // 64 rows x 4 chunks(8)
  for (int k0 = 0; k0 < 16; ++k0) {
    __syncthreads();
    *reinterpret_cast<uint4*>(&As[srow][sc8 * 8]) =
        *reinterpret_cast<const uint4*>(&Of[(size_t)(by * 64 + srow) * D_MODEL + k0 * 32 + sc8 * 8]);
    *reinterpret_cast<uint4*>(&Bs[srow][sc8 * 8]) =
        *reinterpret_cast<const uint4*>(&Bt[(size_t)(bx * 64 + srow) * D_MODEL + k0 * 32 + sc8 * 8]);
    __syncthreads();
    v8h ah[2], bh[2];
#pragma unroll
    for (int i = 0; i < 2; ++i) {
      ah[i] = *reinterpret_cast<const v8h*>(&As[wr * 32 + i * 16 + lx][g * 8]);
      bh[i] = *reinterpret_cast<const v8h*>(&Bs[wc * 32 + i * 16 + lx][g * 8]);
    }
#pragma unroll
    for (int i = 0; i < 2; ++i)
#pragma unroll
      for (int j = 0; j < 2; ++j)
        acc[i][j] = mfma16h(ah[i], bh[j], acc[i][j]);
  }
#pragma unroll
  for (int j = 0; j < 2; ++j) {
    const int col = bx * 64 + wc * 32 + j * 16 + lx;
    const float bj = bo[col];
#pragma unroll
    for (int i = 0; i < 2; ++i)
#pragma unroll
      for (int r = 0; r < 4; ++r) {
        const int row = by * 64 + wr * 32 + i * 16 + g * 4 + r;
        out[(size_t)row * D_MODEL + col] = acc[i][j][r] + bj;
      }
  }
}

// ---------------------------------------------------------------------------
extern "C" void kernel_launch(void* const* d_in, const int* in_sizes, int n_in,
                              void* d_out, int out_size, void* d_ws, size_t ws_size,
                              hipStream_t stream) {
  (void)in_sizes; (void)n_in; (void)out_size; (void)ws_size;
  const float* x  = (const float*)d_in[0];
  const float* cfg= (const float*)d_in[1];
  const float* Wq = (const float*)d_in[2];
  const float* bq = (const float*)d_in[3];
  const float* Wk = (const float*)d_in[4];
  const float* bk = (const float*)d_in[5];
  const float* Wv = (const float*)d_in[6];
  const float* bv = (const float*)d_in[7];
  const float* Wo = (const float*)d_in[8];
  const float* bo = (const float*)d_in[9];
  float* out = (float*)d_out;

  char* p = (char*)d_ws;
  const size_t PL = (size_t)NSEQ * D_MODEL * sizeof(_Float16);   // 2 MiB
  _Float16* Wth = (_Float16*)p;        p += 4 * (size_t)WPLANE * sizeof(_Float16);
  _Float16* xhp = (_Float16*)p;        p += PL;
  _Float16* Qp  = (_Float16*)p;        p += PL;
  _Float16* Kp  = (_Float16*)p;        p += PL;
  _Float16* Vtb = (_Float16*)p;        p += PL;
  _Float16* Of  = (_Float16*)p;        p += PL;
  float*  Qn  = (float*)p;             p += (size_t)NHEADS * NSEQ * sizeof(float);
  float*  Kn  = (float*)p;             p += (size_t)NHEADS * NSEQ * sizeof(float);
  _Float16* Opart = (_Float16*)p;      p += (size_t)NHEADS * NCHUNK * 8192 * sizeof(_Float16);
  float*  Npart = (float*)p;

  prep_wx<<<dim3(8, 8, 5), 256, 0, stream>>>(Wq, Wk, Wv, Wo, x, Wth, xhp);
  qkv_gemm<<<dim3(8, 32, 3), 256, 0, stream>>>(xhp, Wth, bq, bk, bv,
                                               Qp, Kp, Vtb, Qn, Kn);
  attn<<<dim3(NCHUNK * NHEADS), 512, 0, stream>>>(Qp, Kp, Vtb, Qn, Kn, cfg,
                                                  Opart, Npart);
  reduce_o<<<dim3(64, NHEADS), 256, 0, stream>>>(Opart, Npart, Of);
  o_gemm<<<dim3(8, 32), 256, 0, stream>>>(Of, Wth, bo, out);
}

// Round 15
// 78.290 us; speedup vs baseline: 1.4904x; 1.0176x over previous
//
#include <hip/hip_runtime.h>
#include <math.h>

#define D_MODEL 512
#define NHEADS  8
#define NSEQ    2048
#define NBLK    16
#define NCHUNK  72          // sum over m of (m/2+1)
#define EPSF    1e-6f
#define WPLANE  262144      // 512*512 elements per weight plane

typedef _Float16 v8h __attribute__((ext_vector_type(8)));
typedef _Float16 v4h __attribute__((ext_vector_type(4)));
typedef float    v4f __attribute__((ext_vector_type(4)));

static __device__ __forceinline__ v4f mfma16h(v8h a, v8h b, v4f c) {
  return __builtin_amdgcn_mfma_f32_16x16x32_f16(a, b, c, 0, 0, 0);
}

// async global->LDS, 16B per lane; lds base must be wave-uniform.
#define GLLDS(gp, lp)                                                          \
  __builtin_amdgcn_global_load_lds(                                            \
      (const __attribute__((address_space(1))) unsigned int*)(const void*)(gp),\
      (__attribute__((address_space(3))) unsigned int*)(void*)(lp), 16, 0, 0)

// ---------------------------------------------------------------------------
// z<4: W[k][n] fp32 -> Wt[n][k] fp16.  z==4: x fp32 -> fp16 plane.
__global__ __launch_bounds__(256) void prep_wx(const float* __restrict__ W0,
                                               const float* __restrict__ W1,
                                               const float* __restrict__ W2,
                                               const float* __restrict__ W3,
                                               const float* __restrict__ x,
                                               _Float16* __restrict__ Wth,
                                               _Float16* __restrict__ xh) {
  const int z = blockIdx.z;
  const int tid = threadIdx.x;
  if (z == 4) {
    const int wg = blockIdx.y * 8 + blockIdx.x;   // 0..63
    int base = wg * 4096 + tid;                   // float4 index space: 262144
#pragma unroll
    for (int l = 0; l < 16; ++l) {
      int idx = base + l * 256;
      float4 v = reinterpret_cast<const float4*>(x)[idx];
      v4h o;
      o[0] = (_Float16)v.x; o[1] = (_Float16)v.y;
      o[2] = (_Float16)v.z; o[3] = (_Float16)v.w;
      reinterpret_cast<v4h*>(xh)[idx] = o;
    }
    return;
  }
  __shared__ float T[64][68];
  const float* W = (z == 0) ? W0 : (z == 1) ? W1 : (z == 2) ? W2 : W3;
  const int kb = blockIdx.x * 64;
  const int nb = blockIdx.y * 64;
#pragma unroll
  for (int l = 0; l < 4; ++l) {
    int f = tid + l * 256;           // 64 rows(k) x 16 float4(n)
    int row = f >> 4, c4 = f & 15;
    float4 v = *reinterpret_cast<const float4*>(&W[(size_t)(kb + row) * D_MODEL + nb + c4 * 4]);
    T[c4 * 4 + 0][row] = v.x; T[c4 * 4 + 1][row] = v.y;
    T[c4 * 4 + 2][row] = v.z; T[c4 * 4 + 3][row] = v.w;
  }
  __syncthreads();
  _Float16* oh = Wth + (size_t)z * WPLANE;
#pragma unroll
  for (int l = 0; l < 4; ++l) {
    int f = tid + l * 256;           // 64 rows(n) x 16 groups of 4(k)
    int n_ = f >> 4, k4 = f & 15;
    v4h h4;
    h4[0] = (_Float16)T[n_][k4 * 4 + 0];
    h4[1] = (_Float16)T[n_][k4 * 4 + 1];
    h4[2] = (_Float16)T[n_][k4 * 4 + 2];
    h4[3] = (_Float16)T[n_][k4 * 4 + 3];
    *reinterpret_cast<v4h*>(&oh[(size_t)(nb + n_) * D_MODEL + kb + k4 * 4]) = h4;
  }
}

// ---------------------------------------------------------------------------
// Q/K/V projections, 64x64 tiles, grid (8,32,3) = 768 WGs. (unchanged R13)
__global__ __launch_bounds__(256) void qkv_gemm(
    const _Float16* __restrict__ xh, const _Float16* __restrict__ Wth,
    const float* __restrict__ bq, const float* __restrict__ bk,
    const float* __restrict__ bv,
    _Float16* __restrict__ Qp, _Float16* __restrict__ Kp,
    _Float16* __restrict__ Vtb,
    float* __restrict__ Qn_, float* __restrict__ Kn_) {
  __shared__ _Float16 Ah[64][72];
  __shared__ _Float16 Bh[64][72];
  __shared__ float npar[2][64];
  const int z = blockIdx.z;
  const _Float16* Bt = Wth + (size_t)z * WPLANE;
  const float* bias = (z == 0) ? bq : (z == 1) ? bk : bv;
  _Float16* outp = (z == 0) ? Qp : Kp;

  const int bx = blockIdx.x, by = blockIdx.y;
  const int tid = threadIdx.x;
  const int wid = tid >> 6, lane = tid & 63;
  const int wr = wid >> 1, wc = wid & 1;
  const int g = lane >> 4, lx = lane & 15;

  v4f acc[2][2];
#pragma unroll
  for (int i = 0; i < 2; ++i)
#pragma unroll
    for (int j = 0; j < 2; ++j) acc[i][j] = v4f{0.f, 0.f, 0.f, 0.f};

  for (int k0 = 0; k0 < 8; ++k0) {   // K = 512, step 64
    __syncthreads();
#pragma unroll
    for (int l = 0; l < 2; ++l) {
      int f = tid + l * 256;          // 64 rows x 8 chunks(8 fp16)
      int row = f >> 3, c8 = f & 7;
      *reinterpret_cast<uint4*>(&Ah[row][c8 * 8]) =
          *reinterpret_cast<const uint4*>(&xh[(size_t)(by * 64 + row) * D_MODEL + k0 * 64 + c8 * 8]);
      *reinterpret_cast<uint4*>(&Bh[row][c8 * 8]) =
          *reinterpret_cast<const uint4*>(&Bt[(size_t)(bx * 64 + row) * D_MODEL + k0 * 64 + c8 * 8]);
    }
    __syncthreads();
    v8h a[2][2], b[2][2];
#pragma unroll
    for (int i = 0; i < 2; ++i)
#pragma unroll
      for (int ks = 0; ks < 2; ++ks) {
        a[i][ks] = *reinterpret_cast<const v8h*>(&Ah[wr * 32 + i * 16 + lx][ks * 32 + g * 8]);
        b[i][ks] = *reinterpret_cast<const v8h*>(&Bh[wc * 32 + i * 16 + lx][ks * 32 + g * 8]);
      }
#pragma unroll
    for (int i = 0; i < 2; ++i)
#pragma unroll
      for (int j = 0; j < 2; ++j) {
        acc[i][j] = mfma16h(a[i][0], b[j][0], acc[i][j]);
        acc[i][j] = mfma16h(a[i][1], b[j][1], acc[i][j]);
      }
  }

  if (z < 2) {
    float np[2][4];
#pragma unroll
    for (int i = 0; i < 2; ++i)
#pragma unroll
      for (int r = 0; r < 4; ++r) np[i][r] = 0.f;
#pragma unroll
    for (int j = 0; j < 2; ++j) {
      const int col = bx * 64 + wc * 32 + j * 16 + lx;
      const float bj = bias[col];
#pragma unroll
      for (int i = 0; i < 2; ++i)
#pragma unroll
        for (int r = 0; r < 4; ++r) {
          const int row = by * 64 + wr * 32 + i * 16 + g * 4 + r;
          float v = acc[i][j][r] + bj;
          _Float16 hv = (_Float16)v;
          outp[(size_t)row * D_MODEL + col] = hv;
          float vr = (float)hv;
          np[i][r] = fmaf(vr, vr, np[i][r]);
        }
    }
#pragma unroll
    for (int i = 0; i < 2; ++i)
#pragma unroll
      for (int r = 0; r < 4; ++r) {
        float s = np[i][r];
        s += __shfl_xor(s, 1, 64);
        s += __shfl_xor(s, 2, 64);
        s += __shfl_xor(s, 4, 64);
        s += __shfl_xor(s, 8, 64);
        if (lx == 0) npar[wc][wr * 32 + i * 16 + g * 4 + r] = s;
      }
    __syncthreads();
    if (tid < 64) {
      float s = npar[0][tid] + npar[1][tid];
      float* Nout = (z == 0) ? Qn_ : Kn_;
      Nout[bx * NSEQ + by * 64 + tid] = s;
    }
  } else {
    __syncthreads();
    _Float16* Tv = &Ah[0][0];        // [64][72]
#pragma unroll
    for (int j = 0; j < 2; ++j) {
      const int col = wc * 32 + j * 16 + lx;          // local d
      const float bj = bias[bx * 64 + col];
#pragma unroll
      for (int i = 0; i < 2; ++i)
#pragma unroll
        for (int r = 0; r < 4; ++r) {
          const int row = wr * 32 + i * 16 + g * 4 + r;   // local n
          Tv[row * 72 + col] = (_Float16)(acc[i][j][r] + bj);
        }
    }
    __syncthreads();
#pragma unroll
    for (int l = 0; l < 2; ++l) {
      int f = tid + l * 256;         // 0..511: d = f>>3, ch = f&7
      int d = f >> 3, ch = f & 7;
      ushort tmp[8];
#pragma unroll
      for (int jj = 0; jj < 8; ++jj)
        tmp[jj] = ((const ushort*)Tv)[(ch * 8 + jj) * 72 + d];
      *reinterpret_cast<uint4*>(&Vtb[(size_t)(bx * 64 + d) * NSEQ + by * 64 + ch * 8]) =
          *reinterpret_cast<const uint4*>(tmp);
    }
  }
}

// ---------------------------------------------------------------------------
// Attention. grid 576, h = bid&7. 512 thr = 8 waves, LDS 51,200 B -> 3 WG/CU.
// K/V staged via ASYNC global_load_lds into UNPADDED XOR-swizzled LDS
// (physical chunk = logical ^ (row&7); source pre-swizzled, read swizzled).
// Split-Es two-pass (exp half -> PV half) keeps Es at [8][16][68] IN BOUNDS
// (R14's bug: full-width indices on the half-size buffer).
// Pipeline: QK^T0 -> bar -> issue K1 -> score0 -> {exp/PV halves} -> bar
// (drains K1) -> issue V1 -> QK^T1 -> score1 -> exp h0 -> vmcnt(0) -> PV...
__global__ __launch_bounds__(512, 4) void attn(
    const _Float16* __restrict__ Qp, const _Float16* __restrict__ Kp,
    const _Float16* __restrict__ Vtb, const float* __restrict__ Qn,
    const float* __restrict__ Kn, const float* __restrict__ cptr,
    _Float16* __restrict__ Opart, float* __restrict__ Npart)
{
  __shared__ _Float16 KhsF[8192];      // [128 rows][64 halves], swizzled
  __shared__ _Float16 VsF[8192];       // [64 d][128 halves], swizzled
  __shared__ _Float16 Es[8][16][68];   // wave-private HALF-width E buffer
  __shared__ float kns2[256];          // kn for n0 (0..127) and n1 (128..255)

  const int bid = blockIdx.x;
  const int h    = bid & 7;
  const int pid2 = bid >> 3;          // chunk 0..71
  int m = 0, base = 0;
  while (base + (m / 2 + 1) <= pid2) { base += m / 2 + 1; ++m; }
  const int c  = pid2 - base;
  const int n0 = 2 * c;
  const int n1 = (n0 + 1 < m) ? n0 + 1 : m;
  const bool two = (n1 != n0);

  const int tid  = threadIdx.x;
  const int w    = tid >> 6;
  const int lane = tid & 63;
  const int g = lane >> 4, lx = lane & 15;

  const float cc = fmaxf(fabsf(cptr[0]), 1e-6f);
  const float is = rsqrtf(cc);
  const bool is_one = (cc == 1.0f);
  const float two_cc = 2.f * cc;

  const _Float16* Kgh = Kp + h * 64;
  const _Float16* Vgh = Vtb + (size_t)(h * 64) * NSEQ;

  // pre-swizzled source chunk indices (involution key = row&7)
  const int krow0 = tid >> 3;                       // pass0 row; pass1 += 64
  const int klc   = (tid & 7) ^ (krow0 & 7);        // (row+64)&7 == row&7
  const int vd0   = tid >> 4;                       // pass0 d; pass1 += 32
  const int vlc   = (tid & 15) ^ (vd0 & 7);         // (d+32)&7 == d&7

#define ISSUE_K(nn)                                                           \
  do {                                                                        \
    GLLDS(&Kgh[(size_t)((nn) * 128 + krow0) * D_MODEL + klc * 8],             \
          &KhsF[w * 512]);                                                    \
    GLLDS(&Kgh[(size_t)((nn) * 128 + krow0 + 64) * D_MODEL + klc * 8],        \
          &KhsF[4096 + w * 512]);                                             \
  } while (0)
#define ISSUE_V(nn)                                                           \
  do {                                                                        \
    GLLDS(&Vgh[(size_t)vd0 * NSEQ + (nn) * 128 + vlc * 8],                    \
          &VsF[w * 512]);                                                     \
    GLLDS(&Vgh[(size_t)(vd0 + 32) * NSEQ + (nn) * 128 + vlc * 8],             \
          &VsF[4096 + w * 512]);                                              \
  } while (0)

  // ---- prologue: async-stage n0, kn for both iters, Q frags ----
  ISSUE_K(n0);
  ISSUE_V(n0);
  if (tid < 128) kns2[tid] = Kn[h * NSEQ + n0 * 128 + tid];
  else if (two && tid < 256) kns2[tid] = Kn[h * NSEQ + n1 * 128 + (tid - 128)];

  v8h aQ[2];
  {
    const size_t qoff = (size_t)(m * 128 + 16 * w + lx) * D_MODEL + h * 64 + g * 8;
    aQ[0] = *reinterpret_cast<const v8h*>(&Qp[qoff]);
    aQ[1] = *reinterpret_cast<const v8h*>(&Qp[qoff + 32]);
  }
  float qnr[4], qar[4];
#pragma unroll
  for (int r = 0; r < 4; ++r) {
    qnr[r] = Qn[h * NSEQ + m * 128 + 16 * w + g * 4 + r];
    qar[r] = fmaf(-cc, qnr[r], 1.f);
  }

  v4f o_acc[4];
#pragma unroll
  for (int td = 0; td < 4; ++td) o_acc[td] = v4f{0.f, 0.f, 0.f, 0.f};
  float nrm[4] = {0.f, 0.f, 0.f, 0.f};

  __syncthreads();                    // drains gllds + kns2 + everything

  v4f acc[8];
  const int swz = lx & 7;

  // ---- iteration 0 QK^T (K0 resident) ----
#pragma unroll
  for (int tn = 0; tn < 8; ++tn) {
    const int rb = (tn * 16 + lx) * 64;
    v8h b0 = *reinterpret_cast<const v8h*>(&KhsF[rb + ((g ^ swz) * 8)]);
    v8h b1 = *reinterpret_cast<const v8h*>(&KhsF[rb + (((g ^ swz) ^ 4) * 8)]);
    v4f a = v4f{0.f, 0.f, 0.f, 0.f};
    a = mfma16h(aQ[0], b0, a);
    a = mfma16h(aQ[1], b1, a);
    acc[tn] = a;
  }
  if (two) {
    __syncthreads();                  // all QK^T0 K-reads done
    ISSUE_K(n1);                      // async; flies under score0+PV0
  }

#pragma unroll
  for (int it = 0; it < 2; ++it) {
    if (it == 1 && !two) break;
    const int n = (it == 0) ? n0 : n1;
    const int kofs = it * 128;

    if (it == 1) {
      // K1 resident (end-of-it0 barrier drained vmcnt)
#pragma unroll
      for (int tn = 0; tn < 8; ++tn) {
        const int rb = (tn * 16 + lx) * 64;
        v8h b0 = *reinterpret_cast<const v8h*>(&KhsF[rb + ((g ^ swz) * 8)]);
        v8h b1 = *reinterpret_cast<const v8h*>(&KhsF[rb + (((g ^ swz) ^ 4) * 8)]);
        v4f a = v4f{0.f, 0.f, 0.f, 0.f};
        a = mfma16h(aQ[0], b0, a);
        a = mfma16h(aQ[1], b1, a);
        acc[tn] = a;
      }
    }

    // ---- u = arg + sqrt(arg^2-1) ----
    const bool diag = (n == m);
#pragma unroll
    for (int tn = 0; tn < 8; ++tn) {
      const int col = tn * 16 + lx;
      const float knc = kns2[kofs + col];
      const float kac = fmaf(-cc, knc, 1.f);
#pragma unroll
      for (int r = 0; r < 4; ++r) {
        const int rowl = 16 * w + g * 4 + r;
        float dsq = fmaxf(fmaf(-2.f, acc[tn][r], qnr[r] + knc), 0.f);
        float den = fmaxf(qar[r] * kac, EPSF);
        float t = fmaxf(two_cc * dsq * __builtin_amdgcn_rcpf(den), EPSF);
        float u = 1.f + t + __builtin_amdgcn_sqrtf(t * (t + 2.f));
        if (diag && col > rowl) u = __builtin_inff();
        acc[tn][r] = u;
      }
    }

    // ---- full-row reduction (umin for c==1, smax otherwise) ----
    float mred[4];
    if (is_one) {
#pragma unroll
      for (int r = 0; r < 4; ++r) mred[r] = __builtin_inff();
#pragma unroll
      for (int tn = 0; tn < 8; ++tn)
#pragma unroll
        for (int r = 0; r < 4; ++r) mred[r] = fminf(mred[r], acc[tn][r]);
#pragma unroll
      for (int d = 1; d < 16; d <<= 1)
#pragma unroll
        for (int r = 0; r < 4; ++r) mred[r] = fminf(mred[r], __shfl_xor(mred[r], d, 64));
    } else {
#pragma unroll
      for (int r = 0; r < 4; ++r) mred[r] = -__builtin_inff();
#pragma unroll
      for (int tn = 0; tn < 8; ++tn)
#pragma unroll
        for (int r = 0; r < 4; ++r) {
          float s = -__logf(acc[tn][r]) * is;
          acc[tn][r] = s;
          mred[r] = fmaxf(mred[r], s);
        }
#pragma unroll
      for (int d = 1; d < 16; d <<= 1)
#pragma unroll
        for (int r = 0; r < 4; ++r) mred[r] = fmaxf(mred[r], __shfl_xor(mred[r], d, 64));
    }

    // ---- two halves: exp -> Es(half, IN BOUNDS) -> PV(half) ----
#pragma unroll
    for (int half = 0; half < 2; ++half) {
#pragma unroll
      for (int tn2 = 0; tn2 < 4; ++tn2) {
        const int tn = half * 4 + tn2;
#pragma unroll
        for (int r = 0; r < 4; ++r) {
          float e = is_one ? mred[r] * __builtin_amdgcn_rcpf(acc[tn][r])
                           : __expf(acc[tn][r] - mred[r]);
          nrm[r] += e;
          Es[w][g * 4 + r][tn2 * 16 + lx] = (_Float16)e;
        }
      }
      if (it == 1 && half == 0) {
        // V1 must have landed (only outstanding vmem) + Es writes drained
        asm volatile("s_waitcnt vmcnt(0) lgkmcnt(0)" ::: "memory");
      } else {
        asm volatile("s_waitcnt lgkmcnt(0)" ::: "memory");
      }
      __builtin_amdgcn_sched_barrier(0);
#pragma unroll
      for (int ks2 = 0; ks2 < 2; ++ks2) {
        const int ks = half * 2 + ks2;
        v8h ea = *reinterpret_cast<const v8h*>(&Es[w][lx][ks2 * 32 + g * 8]);
#pragma unroll
        for (int td = 0; td < 4; ++td) {
          v8h vb = *reinterpret_cast<const v8h*>(
              &VsF[(td * 16 + lx) * 128 + (((ks * 4 + g) ^ swz) * 8)]);
          o_acc[td] = mfma16h(ea, vb, o_acc[td]);
        }
      }
    }

    if (it == 0 && two) {
      __syncthreads();                // Vs reads done; drains K1 arrival too
      ISSUE_V(n1);                    // async; flies under QK^T1+score1
    }
  }

  // ---- norm reduce across lx ----
#pragma unroll
  for (int d = 1; d < 16; d <<= 1)
#pragma unroll
    for (int r = 0; r < 4; ++r) nrm[r] += __shfl_xor(nrm[r], d, 64);

  // ---- PERMUTED fp16 Opart store: 128B contiguous per instruction ----
  _Float16* Op = Opart + ((size_t)h * NCHUNK + pid2) * 8192;
#pragma unroll
  for (int td = 0; td < 4; ++td)
#pragma unroll
    for (int r = 0; r < 4; ++r)
      Op[(size_t)(((w * 4 + td) * 4) + r) * 64 + lane] = (_Float16)o_acc[td][r];

  // ---- Npart shuffle-gather: lane j<16 -> one 64B store per wave ----
  {
    const int sel = lane & 3;
    float tmp = (sel == 0) ? nrm[0] : (sel == 1) ? nrm[1] : (sel == 2) ? nrm[2] : nrm[3];
    const int src = ((lane >> 2) & 3) * 16 + (lane & 3);
    float nval = __shfl(tmp, src, 64);
    if (lane < 16)
      Npart[((size_t)h * NCHUNK + pid2) * 128 + 16 * w + lane] = nval;
  }
#undef ISSUE_K
#undef ISSUE_V
}

// ---------------------------------------------------------------------------
// Sum PERMUTED fp16 partials over chunks, un-permute via LDS, normalize
// -> Of (fp16). grid (64, 8): 32 rows per WG. (unchanged)
__global__ __launch_bounds__(256) void reduce_o(const _Float16* __restrict__ Opart,
                                                const float* __restrict__ Npart,
                                                _Float16* __restrict__ Of) {
  const int mq = blockIdx.x;
  const int mm = mq >> 2;
  const int rq = (mq & 3) * 32;
  const int h  = blockIdx.y;
  const int tid = threadIdx.x;
  int base = 0;
  for (int k = 0; k < mm; ++k) base += k / 2 + 1;
  const int nch = mm / 2 + 1;

  __shared__ float T[32][68];
  __shared__ float innorm[32];
  if (tid < 32) {
    float s = 0.f;
    for (int cI = 0; cI < nch; ++cI)
      s += Npart[((size_t)h * NCHUNK + base + cI) * 128 + rq + tid];
    innorm[tid] = 1.f / fmaxf(s, EPSF);
  }
  const int wbase = rq >> 4;
#pragma unroll
  for (int l = 0; l < 8; ++l) {
    int idx = tid + l * 256;          // 0..2047
    int lane = idx & 63;
    int sub  = idx >> 6;              // (wloc*4+td)*4 + r
    int r = sub & 3, td = (sub >> 2) & 3, wloc = sub >> 4;
    int w = wbase + wloc;
    const size_t off = (size_t)((w * 4 + td) * 4 + r) * 64 + lane;
    float s = 0.f;
    for (int cI = 0; cI < nch; ++cI)
      s += (float)Opart[((size_t)h * NCHUNK + base + cI) * 8192 + off];
    int row = 16 * wloc + 4 * (lane >> 4) + r;   // local row in [0,32)
    int col = td * 16 + (lane & 15);
    T[row][col] = s;
  }
  __syncthreads();
#pragma unroll
  for (int l = 0; l < 2; ++l) {
    int f = tid + l * 256;            // 0..511 : 32 rows x 16 v4h
    int row = f >> 4, c4 = f & 15;
    float inv = innorm[row];
    v4h o4;
    o4[0] = (_Float16)(T[row][c4 * 4 + 0] * inv);
    o4[1] = (_Float16)(T[row][c4 * 4 + 1] * inv);
    o4[2] = (_Float16)(T[row][c4 * 4 + 2] * inv);
    o4[3] = (_Float16)(T[row][c4 * 4 + 3] * inv);
    *reinterpret_cast<v4h*>(
        &Of[(size_t)(mm * 128 + rq + row) * D_MODEL + h * 64 + c4 * 4]) = o4;
  }
}

// ---------------------------------------------------------------------------
// out = Of @ Wo + bo, 1-term fp16. 64x64 tiles, grid (8,32). (unchanged)
__global__ __launch_bounds__(256) void o_gemm(const _Float16* __restrict__ Of,
                                              const _Float16* __restrict__ Wth,
                                              const float* __restrict__ bo,
                                              float* __restrict__ out) {
  __shared__ _Float16 As[64][40], Bs[64][40];
  const _Float16* Bt = Wth + (size_t)3 * WPLANE;
  const int bx = blockIdx.x, by = blockIdx.y;
  const int tid = threadIdx.x;
  const int wid = tid >> 6, lane = tid & 63;
  const int wr = wid >> 1, wc = wid & 1;
  const int g = lane >> 4, lx = lane & 15;

  v4f acc[2][2];
#pragma unroll
  for (int i = 0; i < 2; ++i)
#pragma unroll
    for (int j = 0; j < 2; ++j) acc[i][j] = v4f{0.f, 0.f, 0.f, 0.f};

  const int srow = tid >> 2, sc8 = tid & 3;   // 64 rows x 4 chunks(8)
  for (int k0 = 0; k0 < 16; ++k0) {
    __syncthreads();
    *reinterpret_cast<uint4*>(&As[srow][sc8 * 8]) =
        *reinterpret_cast<const uint4*>(&Of[(size_t)(by * 64 + srow) * D_MODEL + k0 * 32 + sc8 * 8]);
    *reinterpret_cast<uint4*>(&Bs[srow][sc8 * 8]) =
        *reinterpret_cast<const uint4*>(&Bt[(size_t)(bx * 64 + srow) * D_MODEL + k0 * 32 + sc8 * 8]);
    __syncthreads();
    v8h ah[2], bh[2];
#pragma unroll
    for (int i = 0; i < 2; ++i) {
      ah[i] = *reinterpret_cast<const v8h*>(&As[wr * 32 + i * 16 + lx][g * 8]);
      bh[i] = *reinterpret_cast<const v8h*>(&Bs[wc * 32 + i * 16 + lx][g * 8]);
    }
#pragma unroll
    for (int i = 0; i < 2; ++i)
#pragma unroll
      for (int j = 0; j < 2; ++j)
        acc[i][j] = mfma16h(ah[i], bh[j], acc[i][j]);
  }
#pragma unroll
  for (int j = 0; j < 2; ++j) {
    const int col = bx * 64 + wc * 32 + j * 16 + lx;
    const float bj = bo[col];
#pragma unroll
    for (int i = 0; i < 2; ++i)
#pragma unroll
      for (int r = 0; r < 4; ++r) {
        const int row = by * 64 + wr * 32 + i * 16 + g * 4 + r;
        out[(size_t)row * D_MODEL + col] = acc[i][j][r] + bj;
      }
  }
}

// ---------------------------------------------------------------------------
extern "C" void kernel_launch(void* const* d_in, const int* in_sizes, int n_in,
                              void* d_out, int out_size, void* d_ws, size_t ws_size,
                              hipStream_t stream) {
  (void)in_sizes; (void)n_in; (void)out_size; (void)ws_size;
  const float* x  = (const float*)d_in[0];
  const float* cfg= (const float*)d_in[1];
  const float* Wq = (const float*)d_in[2];
  const float* bq = (const float*)d_in[3];
  const float* Wk = (const float*)d_in[4];
  const float* bk = (const float*)d_in[5];
  const float* Wv = (const float*)d_in[6];
  const float* bv = (const float*)d_in[7];
  const float* Wo = (const float*)d_in[8];
  const float* bo = (const float*)d_in[9];
  float* out = (float*)d_out;

  char* p = (char*)d_ws;
  const size_t PL = (size_t)NSEQ * D_MODEL * sizeof(_Float16);   // 2 MiB
  _Float16* Wth = (_Float16*)p;        p += 4 * (size_t)WPLANE * sizeof(_Float16);
  _Float16* xhp = (_Float16*)p;        p += PL;
  _Float16* Qp  = (_Float16*)p;        p += PL;
  _Float16* Kp  = (_Float16*)p;        p += PL;
  _Float16* Vtb = (_Float16*)p;        p += PL;
  _Float16* Of  = (_Float16*)p;        p += PL;
  float*  Qn  = (float*)p;             p += (size_t)NHEADS * NSEQ * sizeof(float);
  float*  Kn  = (float*)p;             p += (size_t)NHEADS * NSEQ * sizeof(float);
  _Float16* Opart = (_Float16*)p;      p += (size_t)NHEADS * NCHUNK * 8192 * sizeof(_Float16);
  float*  Npart = (float*)p;

  prep_wx<<<dim3(8, 8, 5), 256, 0, stream>>>(Wq, Wk, Wv, Wo, x, Wth, xhp);
  qkv_gemm<<<dim3(8, 32, 3), 256, 0, stream>>>(xhp, Wth, bq, bk, bv,
                                               Qp, Kp, Vtb, Qn, Kn);
  attn<<<dim3(NCHUNK * NHEADS), 512, 0, stream>>>(Qp, Kp, Vtb, Qn, Kn, cfg,
                                                  Opart, Npart);
  reduce_o<<<dim3(64, NHEADS), 256, 0, stream>>>(Opart, Npart, Of);
  o_gemm<<<dim3(8, 32), 256, 0, stream>>>(Of, Wth, bo, out);
}